// Round 19
// baseline (392.692 us; speedup 1.0000x reference)
//
#include <hip/hip_runtime.h>

namespace {

constexpr int NB = 32, NL = 1024, NC = 128, NP = 96, KW = 5;
constexpr float INV_SQRT2 = 0.70710678118654752440f;
constexpr size_t SEG = (size_t)NB * NC;   // 4096
constexpr int CT = 64;                    // output columns per conv block

typedef unsigned short u16;
typedef __attribute__((ext_vector_type(4))) u16 u16x4;
typedef __attribute__((ext_vector_type(8))) u16 u16x8;
typedef __attribute__((ext_vector_type(8))) short short8;
typedef __attribute__((ext_vector_type(4))) float f32x4;

__device__ inline u16 f2bf(float f) {
  unsigned u = __float_as_uint(f);
  u += 0x7fff + ((u >> 16) & 1);
  return (u16)(u >> 16);
}

__device__ inline float ftanh(float x) {
  float e = __expf(2.f * x);
  return 1.f - 2.f / (e + 1.f);
}

// ---------------- stats stage 1 ----------------
__global__ void stats1(const float* __restrict__ x, const float* __restrict__ mask,
                       float* __restrict__ part) {
  int b = blockIdx.x, s = blockIdx.y;
  int tid = threadIdx.x;
  int c = tid & 127, lh = tid >> 7;
  const float* xb = x + (size_t)b * NL * NC;
  const float* mb = mask + (size_t)b * NL * NC;
  float s_all = 0.f, d1 = 0.f, sm = 0.f, sm2 = 0.f, cnz = 0.f;
#pragma unroll 4
  for (int i = 0; i < 32; ++i) {
    int l = s * 64 + lh + 2 * i;
    float v = xb[(size_t)l * NC + c];
    float m = mb[(size_t)l * NC + c];
    s_all += v;
    d1 += (m == 1.f) ? 1.f : 0.f;
    bool nz = (m != 0.f);
    float vm = nz ? v : 0.f;
    sm += vm;
    sm2 += vm * v;
    cnz += nz ? 1.f : 0.f;
  }
  __shared__ float red[5][256];
  red[0][tid] = s_all; red[1][tid] = d1; red[2][tid] = sm;
  red[3][tid] = sm2;   red[4][tid] = cnz;
  __syncthreads();
  if (lh == 0) {
    float* pp = part + ((size_t)(b * 16 + s) * 5) * NC + c;
#pragma unroll
    for (int q = 0; q < 5; ++q) pp[q * NC] = red[q][c] + red[q][c + 128];
  }
}

__global__ void stats2(const float* __restrict__ part, float* __restrict__ means,
                       float* __restrict__ stdev) {
  int b = blockIdx.x, c = threadIdx.x;
  float s_all = 0.f, d1 = 0.f, sm = 0.f, sm2 = 0.f, cnz = 0.f;
  for (int s = 0; s < 16; ++s) {
    const float* pp = part + ((size_t)(b * 16 + s) * 5) * NC + c;
    s_all += pp[0];
    d1    += pp[NC];
    sm    += pp[2 * NC];
    sm2   += pp[3 * NC];
    cnz   += pp[4 * NC];
  }
  float mn = s_all / d1;
  float varsum = sm2 - 2.f * mn * sm + mn * mn * cnz;
  means[b * NC + c] = mn;
  stdev[b * NC + c] = sqrtf(varsum / d1 + 1e-5f);
}

// ---------------- normalize + transpose (B,L,C) -> (B,C,L) ----------------
__global__ void norm_transpose(const float* __restrict__ x, const float* __restrict__ mask,
                               const float* __restrict__ means, const float* __restrict__ stdev,
                               float* __restrict__ xt) {
  __shared__ float tile[32][33];
  int b = blockIdx.x;
  int l0 = blockIdx.y * 32;
  int c0 = blockIdx.z * 32;
  int tx = threadIdx.x;
  int ty = threadIdx.y;
  for (int i = ty; i < 32; i += 8) {
    int l = l0 + i, c = c0 + tx;
    float v = x[((size_t)b * NL + l) * NC + c];
    float m = mask[((size_t)b * NL + l) * NC + c];
    float val = (m == 0.f) ? 0.f : (v - means[b * NC + c]);
    tile[i][tx] = val / stdev[b * NC + c];
  }
  __syncthreads();
  for (int i = ty; i < 32; i += 8) {
    xt[((size_t)b * NC + c0 + i) * NL + l0 + tx] = tile[tx][i];
  }
}

// ---------------- Haar transform per row, bf16 out ----------------
__global__ void haar_kernel(const float* __restrict__ xt, u16* __restrict__ freqb) {
  int row = blockIdx.x;
  __shared__ float h[1024], t2[512];
  const float* src = xt + (size_t)row * NL;
  u16* dst = freqb + (size_t)row * NL;
  for (int i = threadIdx.x; i < 1024; i += 256) h[i] = src[i];
  __syncthreads();
  int n = 1024;
  while (n > 1) {
    int half = n >> 1;
    for (int i = threadIdx.x; i < half; i += 256) {
      float e = h[2 * i], o = h[2 * i + 1];
      dst[half + i] = f2bf((e - o) * INV_SQRT2);
      t2[i] = (e + o) * INV_SQRT2;
    }
    __syncthreads();
    for (int i = threadIdx.x; i < half; i += 256) h[i] = t2[i];
    __syncthreads();
    n = half;
  }
  if (threadIdx.x == 0) dst[0] = f2bf(h[0]);
}

// ---------------- f32 -> bf16, two tensors in one launch ----------------
__global__ void cvt2(const float* __restrict__ in1, const float* __restrict__ in2,
                     u16* __restrict__ o1, u16* __restrict__ o2, int n4) {
  int i = blockIdx.x * 256 + threadIdx.x;
  const float* in = (i < n4) ? in1 : in2;
  u16* op = (i < n4) ? o1 : o2;
  int j = (i < n4) ? i : i - n4;
  if (j < n4) {
    const float4 v = *reinterpret_cast<const float4*>(in + (size_t)j * 4);
    u16x4 o;
    o.x = f2bf(v.x); o.y = f2bf(v.y); o.z = f2bf(v.z); o.w = f2bf(v.w);
    *reinterpret_cast<u16x4*>(op + (size_t)j * 4) = o;
  }
}

// ---------------- pack conv weights [60][co][ci][k] -> [60][k][co][ci] bf16, both sets ----------------
__global__ void pack2(const float* __restrict__ w1, const float* __restrict__ w2,
                      u16* __restrict__ wp1, u16* __restrict__ wp2) {
  int idx = blockIdx.x * 256 + threadIdx.x;
  const int NW = 60 * 128 * 128;
  const float* w = (idx < NW) ? w1 : w2;
  u16* wp = (idx < NW) ? wp1 : wp2;
  int j = (idx < NW) ? idx : idx - NW;
  if (j < NW) {
    int ci = j & 127;
    int co = (j >> 7) & 127;
    int n = j >> 14;
    const float* src = w + (size_t)j * 5;
    size_t base = (size_t)n * (5 * 128 * 128) + (size_t)co * 128 + ci;
#pragma unroll
    for (int k = 0; k < 5; ++k)
      wp[base + (size_t)k * 16384] = f2bf(src[k]);
  }
}

// ---------------- bf16 MFMA GEMM NT, 128m x 128n x 64k, XCD chunk + reg double-buffer ----------------
__global__ __launch_bounds__(256) void gemm_n128(const u16* __restrict__ A,
                                                 const u16* __restrict__ Bw,
                                                 u16* __restrict__ Cb,
                                                 int M, int N, int K, int CM, int CN) {
  __shared__ __align__(16) char sAB[256 * 128];
  int GX = gridDim.x;
  int h = blockIdx.y * GX + blockIdx.x;
  int xcd = h & 7, loc = h >> 3;
  int lm = loc / CN, ln = loc - lm * CN;
  int cnch = GX / CN;
  int m0 = ((xcd / cnch) * CM + lm) * 128;
  int n0 = ((xcd % cnch) * CN + ln) * 128;
  int tid = threadIdx.x;
  int lane = tid & 63, wv = tid >> 6;
  int wm = (wv >> 1) * 64, wn = (wv & 1) * 64;
  int lg = lane >> 4, l15 = lane & 15;

  const u16* srcb[8];
  int swo[8];
#pragma unroll
  for (int pass = 0; pass < 8; ++pass) {
    int o = pass * 4096 + tid * 16;
    int cb = o & 127;
    int row;
    if (pass < 4) {
      row = o >> 7;
      srcb[pass] = A + (size_t)(m0 + row) * K + (cb >> 1);
    } else {
      int rb = (o - 16384) >> 7;
      row = 128 + rb;
      srcb[pass] = Bw + (size_t)(n0 + rb) * K + (cb >> 1);
    }
    swo[pass] = row * 128 + (cb ^ ((row & 7) << 4));
  }

  f32x4 zero = {0.f, 0.f, 0.f, 0.f};
  f32x4 acc[4][4];
#pragma unroll
  for (int i = 0; i < 4; ++i)
#pragma unroll
    for (int j = 0; j < 4; ++j) acc[i][j] = zero;

  u16x8 st[8];
#pragma unroll
  for (int p = 0; p < 8; ++p) st[p] = *(const u16x8*)(srcb[p]);

  for (int k0 = 0; k0 < K; k0 += 64) {
    __syncthreads();
#pragma unroll
    for (int p = 0; p < 8; ++p) *(u16x8*)(sAB + swo[p]) = st[p];
    __syncthreads();
    if (k0 + 64 < K) {
#pragma unroll
      for (int p = 0; p < 8; ++p) st[p] = *(const u16x8*)(srcb[p] + k0 + 64);
    }
#pragma unroll
    for (int ks = 0; ks < 2; ++ks) {
      int kb = ks * 64 + lg * 16;
      short8 a[4], bbf[4];
#pragma unroll
      for (int mt = 0; mt < 4; ++mt) {
        int rr = wm + mt * 16 + l15;
        a[mt] = *(const short8*)(sAB + rr * 128 + (kb ^ ((rr & 7) << 4)));
      }
#pragma unroll
      for (int nt = 0; nt < 4; ++nt) {
        int rr = 128 + wn + nt * 16 + l15;
        bbf[nt] = *(const short8*)(sAB + rr * 128 + (kb ^ ((rr & 7) << 4)));
      }
#pragma unroll
      for (int mt = 0; mt < 4; ++mt)
#pragma unroll
        for (int nt = 0; nt < 4; ++nt)
          acc[mt][nt] = __builtin_amdgcn_mfma_f32_16x16x32_bf16(a[mt], bbf[nt], acc[mt][nt], 0, 0, 0);
    }
  }
#pragma unroll
  for (int mt = 0; mt < 4; ++mt)
#pragma unroll
    for (int nt = 0; nt < 4; ++nt)
#pragma unroll
      for (int r = 0; r < 4; ++r) {
        int row = m0 + wm + mt * 16 + lg * 4 + r;
        int col = n0 + wn + nt * 16 + l15;
        float v = acc[mt][nt][r];
        v = v > 0.f ? v : 0.f;
        Cb[(size_t)row * N + col] = f2bf(v);
      }
}

// ---------------- bf16 MFMA GEMM NT, 128m x 64n x 64k (gemm2: sigmoid -> f32) ----------------
__global__ __launch_bounds__(256) void gemm_mfma(const u16* __restrict__ A,
                                                 const u16* __restrict__ Bw,
                                                 float* __restrict__ Cf,
                                                 int M, int N, int K, int CM, int CN) {
  __shared__ __align__(16) char sAB[(128 + 64) * 128];
  int GX = gridDim.x;
  int h = blockIdx.y * GX + blockIdx.x;
  int xcd = h & 7, loc = h >> 3;
  int lm = loc / CN, ln = loc - lm * CN;
  int cnch = GX / CN;
  int m0 = ((xcd / cnch) * CM + lm) * 128;
  int n0 = ((xcd % cnch) * CN + ln) * 64;
  int tid = threadIdx.x;
  int lane = tid & 63, wv = tid >> 6;
  int wm = (wv >> 1) * 64, wn = (wv & 1) * 32;
  int lg = lane >> 4, l15 = lane & 15;

  const u16* srcb[6];
  int swo[6];
#pragma unroll
  for (int pass = 0; pass < 6; ++pass) {
    int o = pass * 4096 + tid * 16;
    int cb = o & 127;
    int row;
    if (pass < 4) {
      row = o >> 7;
      srcb[pass] = A + (size_t)(m0 + row) * K + (cb >> 1);
    } else {
      int rb = (o - 16384) >> 7;
      row = 128 + rb;
      srcb[pass] = Bw + (size_t)(n0 + rb) * K + (cb >> 1);
    }
    swo[pass] = row * 128 + (cb ^ ((row & 7) << 4));
  }

  f32x4 zero = {0.f, 0.f, 0.f, 0.f};
  f32x4 acc[4][2];
#pragma unroll
  for (int i = 0; i < 4; ++i)
#pragma unroll
    for (int j = 0; j < 2; ++j) acc[i][j] = zero;

  u16x8 st[6];
#pragma unroll
  for (int p = 0; p < 6; ++p) st[p] = *(const u16x8*)(srcb[p]);

  for (int k0 = 0; k0 < K; k0 += 64) {
    __syncthreads();
#pragma unroll
    for (int p = 0; p < 6; ++p) *(u16x8*)(sAB + swo[p]) = st[p];
    __syncthreads();
    if (k0 + 64 < K) {
#pragma unroll
      for (int p = 0; p < 6; ++p) st[p] = *(const u16x8*)(srcb[p] + k0 + 64);
    }
#pragma unroll
    for (int ks = 0; ks < 2; ++ks) {
      int kb = ks * 64 + lg * 16;
      short8 a[4], bbf[2];
#pragma unroll
      for (int mt = 0; mt < 4; ++mt) {
        int rr = wm + mt * 16 + l15;
        a[mt] = *(const short8*)(sAB + rr * 128 + (kb ^ ((rr & 7) << 4)));
      }
#pragma unroll
      for (int nt = 0; nt < 2; ++nt) {
        int rr = 128 + wn + nt * 16 + l15;
        bbf[nt] = *(const short8*)(sAB + rr * 128 + (kb ^ ((rr & 7) << 4)));
      }
#pragma unroll
      for (int mt = 0; mt < 4; ++mt)
#pragma unroll
        for (int nt = 0; nt < 2; ++nt)
          acc[mt][nt] = __builtin_amdgcn_mfma_f32_16x16x32_bf16(a[mt], bbf[nt], acc[mt][nt], 0, 0, 0);
    }
  }
#pragma unroll
  for (int mt = 0; mt < 4; ++mt)
#pragma unroll
    for (int nt = 0; nt < 2; ++nt)
#pragma unroll
      for (int r = 0; r < 4; ++r) {
        int row = m0 + wm + mt * 16 + lg * 4 + r;
        int col = n0 + wn + nt * 16 + l15;
        Cf[(size_t)row * N + col] = 1.f / (1.f + __expf(-acc[mt][nt][r]));
      }
}

// ---------------- fused LayerNorm + combine: xt = xt * LN(lr) + pe ----------------
__global__ void ln_combine(const float* __restrict__ lr, float* __restrict__ xt,
                           const float* __restrict__ g, const float* __restrict__ bta) {
  int row = blockIdx.x;          // b*NC + c
  int c = row & 127;
  const float* p = lr + (size_t)row * 1024;
  int tid = threadIdx.x;
  float v[4];
#pragma unroll
  for (int i = 0; i < 4; ++i) v[i] = p[tid + 256 * i];
  __shared__ float red[256];
  red[tid] = v[0] + v[1] + v[2] + v[3];
  __syncthreads();
  for (int off = 128; off > 0; off >>= 1) {
    if (tid < off) red[tid] += red[tid + off];
    __syncthreads();
  }
  float mu = red[0] * (1.f / 1024.f);
  __syncthreads();
  float sq = 0.f;
#pragma unroll
  for (int i = 0; i < 4; ++i) { float d = v[i] - mu; sq += d * d; }
  red[tid] = sq;
  __syncthreads();
  for (int off = 128; off > 0; off >>= 1) {
    if (tid < off) red[tid] += red[tid + off];
    __syncthreads();
  }
  float rs = rsqrtf(red[0] * (1.f / 1024.f) + 1e-6f);
  int t = c & 63;
  float inv = __expf(-0.14619589f * (float)t);
  float* xr = xt + (size_t)row * 1024;
#pragma unroll
  for (int i = 0; i < 4; ++i) {
    int l = tid + 256 * i;
    float lrv = (v[i] - mu) * rs * g[l] + bta[l];
    float st = (float)l * inv;
    float pe = (c < 64) ? sinf(st) : cosf(st);
    xr[l] = xr[l] * lrv + pe;
  }
}

// ================= fused ccb (conv1 -> leaky -> conv2 -> combine), weights in registers ======
// VAR 0: ccb0/ccb1 pair (g=z&1): in = parent parity (1-g); out = xeo[p*2+g] = x_par*exp(tanh)
// VAR 1: ccb2/ccb3 pair: in = xeo[p*2 + (g?0:1)]; out = child[2p+g] = xeo[p*2+g] +/- tanh
// sdat row ii = x[t0-8+ii] (clamped); conv1 pos j -> mid_storage[t0-4+j] in smid row j;
// conv2 z[t0+t] reads mid_storage[t0+t+k] = smid row t+k+4.
// Weight pipeline: per-lane 16B global loads into u16x8 wreg[4][2], statically indexed,
// 4 steps ahead; compiler inserts per-register waitcnts (no LDS round-trip).
template <int VAR>
__global__ __launch_bounds__(256) void ccb_fused(
    const float* __restrict__ inF, float* __restrict__ outF,
    const u16* __restrict__ wp1, const u16* __restrict__ wp2,
    const float* __restrict__ b1, const float* __restrict__ b2,
    int d, int Tn) {
  __shared__ __align__(16) char sdat[84 * 256];   // x rows t0-8 .. t0+75 (clamped)
  __shared__ __align__(16) char smid[80 * 256];   // mid_storage[t0-4 .. t0+75]
  int gx = gridDim.x, gy = gridDim.y;
  int total = gx * gy * gridDim.z;
  int hidx = (blockIdx.z * gy + blockIdx.y) * gx + blockIdx.x;
  int lidx = (hidx & 7) * (total >> 3) + (hidx >> 3);
  int b = lidx % gx;
  int rest = lidx / gx;
  int ty = rest % gy;
  int z = rest / gy;
  int p = z >> 1, g = z & 1;
  int node = 0;
  for (int i2 = d - 1; i2 >= 0; --i2) {
    int bit = (p >> i2) & 1;
    int dd = d - 1 - i2;
    node += 1 + bit * ((1 << (3 - dd)) - 1);
  }
  int t0 = CT * ty;
  int tid = threadIdx.x;
  int wq = tid >> 6;
  int lane = tid & 63, wv = wq;
  int lg = lane >> 4, l15 = lane & 15;

  int widx = node * 4 + VAR * 2 + g;
  const u16* W1 = wp1 + (size_t)widx * (5 * 128 * 128);
  const u16* W2 = wp2 + (size_t)widx * (5 * 128 * 128);
  const float* B1 = b1 + (size_t)widx * 128;
  const float* B2 = b2 + (size_t)widx * 128;
  f32x4 bv1[2], bv2[2];
#pragma unroll
  for (int mt = 0; mt < 2; ++mt) {
    bv1[mt] = *(const f32x4*)(B1 + wv * 32 + mt * 16 + lg * 4);
    bv2[mt] = *(const f32x4*)(B2 + wv * 32 + mt * 16 + lg * 4);
  }

  // per-lane weight address helper: step s (0..19 within a conv), output row co
  int co_l[2] = {wv * 32 + l15, wv * 32 + 16 + l15};
  int ciL = lg * 8;

  // ---- issue weight prefetch for steps 0..3 of W1 BEFORE data staging ----
  u16x8 wreg[4][2];
#pragma unroll
  for (int s = 0; s < 4; ++s) {
    int k = s >> 2, ci0 = (s & 3) * 32 + ciL;
#pragma unroll
    for (int mt = 0; mt < 2; ++mt)
      wreg[s][mt] = *(const u16x8*)(W1 + (((size_t)(k * 128 + co_l[mt])) << 7) + ci0);
  }

  // ---- stage x tile: row ii holds x[t0 - 8 + ii], clamped ----
  {
    int i = tid & 63;
#pragma unroll
    for (int rep = 0; rep < 2; ++rep) {
      int ii = i + rep * 64;
      if (ii < 84) {
        int sw0 = (ii & 15) << 4;
        int tt = t0 - 8 + ii;
        tt = tt < 0 ? 0 : (tt >= Tn ? Tn - 1 : tt);
        if (VAR == 0) {
          const float* rp = inF + ((size_t)p * SEG + (size_t)b * NC) * (size_t)(2 * Tn) +
                            2 * tt + (1 - g);
#pragma unroll
          for (int pp = 0; pp < 16; ++pp) {
            int pr = wq * 16 + pp;
            float v0 = rp[(size_t)(2 * pr) * (2 * Tn)];
            float v1 = rp[(size_t)(2 * pr + 1) * (2 * Tn)];
            unsigned pk = (unsigned)f2bf(v0) | ((unsigned)f2bf(v1) << 16);
            *(unsigned*)(sdat + ii * 256 + ((4 * pr) ^ sw0)) = pk;
          }
        } else {
          const float* sp = inF + ((size_t)(p * 2 + (g ? 0 : 1)) * SEG + (size_t)b * NC) * Tn + tt;
#pragma unroll
          for (int pp = 0; pp < 16; ++pp) {
            int pr = wq * 16 + pp;
            unsigned pk = (unsigned)f2bf(sp[(size_t)(2 * pr) * Tn]) |
                          ((unsigned)f2bf(sp[(size_t)(2 * pr + 1) * Tn]) << 16);
            *(unsigned*)(sdat + ii * 256 + ((4 * pr) ^ sw0)) = pk;
          }
        }
      }
    }
  }
  __syncthreads();

  int co_base = wv * 32 + lg * 4;

  // ---- conv1: 20 steps, 5 n-tiles; smid row j = mid_storage[t0-4+j] ----
  f32x4 acc1[2][5];
#pragma unroll
  for (int mt = 0; mt < 2; ++mt)
#pragma unroll
    for (int nt = 0; nt < 5; ++nt) acc1[mt][nt] = bv1[mt];

#pragma unroll
  for (int s = 0; s < 20; ++s) {
    short8 a0 = (short8)wreg[s & 3][0];
    short8 a1 = (short8)wreg[s & 3][1];
    int cbyte = 2 * ((s & 3) * 32 + lg * 8);
    int k = s >> 2;
#pragma unroll
    for (int nt = 0; nt < 5; ++nt) {
      int i = nt * 16 + l15 + k;   // <= 83
      short8 bb = *(const short8*)(sdat + i * 256 + (cbyte ^ ((i & 15) << 4)));
      acc1[0][nt] = __builtin_amdgcn_mfma_f32_16x16x32_bf16(a0, bb, acc1[0][nt], 0, 0, 0);
      acc1[1][nt] = __builtin_amdgcn_mfma_f32_16x16x32_bf16(a1, bb, acc1[1][nt], 0, 0, 0);
    }
    {
      int gs = s + 4;  // global step to prefetch (< 40)
      const u16* W = (gs < 20) ? W1 : W2;
      int ls = (gs < 20) ? gs : gs - 20;
      int kk = ls >> 2, ci0 = (ls & 3) * 32 + ciL;
#pragma unroll
      for (int mt = 0; mt < 2; ++mt)
        wreg[s & 3][mt] = *(const u16x8*)(W + (((size_t)(kk * 128 + co_l[mt])) << 7) + ci0);
    }
  }

  // ---- leaky + write mid tile ----
#pragma unroll
  for (int mt = 0; mt < 2; ++mt)
#pragma unroll
    for (int nt = 0; nt < 5; ++nt) {
      int j = nt * 16 + l15;
      int co0 = co_base + mt * 16;
      u16x4 m;
#pragma unroll
      for (int r = 0; r < 4; ++r) {
        float v = acc1[mt][nt][r];
        v = v > 0.f ? v : 0.01f * v;
        m[r] = f2bf(v);
      }
      *(u16x4*)(smid + j * 256 + ((2 * co0) ^ ((j & 15) << 4))) = m;
    }
  __syncthreads();   // mid visible to all waves

  // ---- conv2: 20 steps, 4 n-tiles; reads smid row t+k+4 ----
  f32x4 acc2[2][4];
#pragma unroll
  for (int mt = 0; mt < 2; ++mt)
#pragma unroll
    for (int nt = 0; nt < 4; ++nt) acc2[mt][nt] = bv2[mt];

#pragma unroll
  for (int sp = 0; sp < 20; ++sp) {
    short8 a0 = (short8)wreg[sp & 3][0];
    short8 a1 = (short8)wreg[sp & 3][1];
    int cbyte = 2 * ((sp & 3) * 32 + lg * 8);
    int k = sp >> 2;
#pragma unroll
    for (int nt = 0; nt < 4; ++nt) {
      int i = nt * 16 + l15 + k + 4;   // +4: smid row j = mid_storage[t0-4+j]  (<= 71)
      short8 bb = *(const short8*)(smid + i * 256 + (cbyte ^ ((i & 15) << 4)));
      acc2[0][nt] = __builtin_amdgcn_mfma_f32_16x16x32_bf16(a0, bb, acc2[0][nt], 0, 0, 0);
      acc2[1][nt] = __builtin_amdgcn_mfma_f32_16x16x32_bf16(a1, bb, acc2[1][nt], 0, 0, 0);
    }
    if (sp + 4 < 20) {
      int ls = sp + 4;
      int kk = ls >> 2, ci0 = (ls & 3) * 32 + ciL;
#pragma unroll
      for (int mt = 0; mt < 2; ++mt)
        wreg[sp & 3][mt] = *(const u16x8*)(W2 + (((size_t)(kk * 128 + co_l[mt])) << 7) + ci0);
    }
  }

  // ---- combine + store ----
  if (VAR == 0) {
    const float* par = inF + ((size_t)p * SEG + (size_t)b * NC) * (size_t)(2 * Tn);
    float* xo_ = outF + ((size_t)(p * 2 + g) * SEG + (size_t)b * NC) * Tn;
#pragma unroll
    for (int mt = 0; mt < 2; ++mt)
#pragma unroll
      for (int nt = 0; nt < 4; ++nt) {
        int t = t0 + nt * 16 + l15;
#pragma unroll
        for (int r = 0; r < 4; ++r) {
          int co = co_base + mt * 16 + r;
          float xv = par[(size_t)co * (2 * Tn) + 2 * t + g];   // g0: xe, g1: xo
          xo_[(size_t)co * Tn + t] = xv * __expf(ftanh(acc2[mt][nt][r]));
        }
      }
  } else {
    const float* xf = inF + ((size_t)(p * 2 + g) * SEG + (size_t)b * NC) * Tn;  // g0: xet, g1: xot
    float* ch = outF + ((size_t)(2 * p + g) * SEG + (size_t)b * NC) * Tn;
#pragma unroll
    for (int mt = 0; mt < 2; ++mt)
#pragma unroll
      for (int nt = 0; nt < 4; ++nt) {
        int t = t0 + nt * 16 + l15;
#pragma unroll
        for (int r = 0; r < 4; ++r) {
          int co = co_base + mt * 16 + r;
          float cv = ftanh(acc2[mt][nt][r]);
          float base = xf[(size_t)co * Tn + t];
          ch[(size_t)co * Tn + t] = g ? (base - cv) : (base + cv);
        }
      }
  }
}

// ---------------- final projection + denorm (gathers leaf layout) ----------------
__global__ void final_kernel(const float* __restrict__ dect, const float* __restrict__ xt,
                             const float* __restrict__ projw, const float* __restrict__ means,
                             const float* __restrict__ stdev, float* __restrict__ out) {
  int b = blockIdx.x, p = blockIdx.y;
  int tid = threadIdx.x;
  const float* w = projw + (size_t)(1024 + p) * 1024;
  const float* x0 = xt + (size_t)b * NC * NL;
  float a[3] = {0.f, 0.f, 0.f};
  for (int l = tid; l < 1024; l += 256) {
    float wv = w[l];
    int rl = l & 7;
    int pb = ((rl & 1) << 2) | (rl & 2) | (rl >> 2);
    int br = (l >> 3) & 1;
    int t = l >> 4;
    const float* dl = dect + ((size_t)(2 * pb + br) * NB + b) * NC * 64 + t;
#pragma unroll
    for (int cc = 0; cc < 3; ++cc)
      a[cc] += wv * (dl[(size_t)cc * 64] + x0[(size_t)cc * NL + l]);
  }
  __shared__ float red[3][256];
  for (int cc = 0; cc < 3; ++cc) red[cc][tid] = a[cc];
  __syncthreads();
  for (int off = 128; off > 0; off >>= 1) {
    if (tid < off) {
      red[0][tid] += red[0][tid + off];
      red[1][tid] += red[1][tid + off];
      red[2][tid] += red[2][tid + off];
    }
    __syncthreads();
  }
  if (tid < 3) {
    out[((size_t)b * NP + p) * 3 + tid] = red[tid][0] * stdev[b * NC + tid] + means[b * NC + tid];
  }
}

}  // namespace

extern "C" void kernel_launch(void* const* d_in, const int* in_sizes, int n_in,
                              void* d_out, int out_size, void* d_ws, size_t ws_size,
                              hipStream_t stream) {
  (void)in_sizes; (void)n_in; (void)out_size; (void)ws_size;
  const float* x_enc = (const float*)d_in[0];
  const float* mask  = (const float*)d_in[1];
  const float* fc1_w = (const float*)d_in[2];
  const float* fc2_w = (const float*)d_in[3];
  const float* ln_g  = (const float*)d_in[4];
  const float* ln_b  = (const float*)d_in[5];
  const float* w1    = (const float*)d_in[6];
  const float* b1    = (const float*)d_in[7];
  const float* w2    = (const float*)d_in[8];
  const float* b2    = (const float*)d_in[9];
  const float* projw = (const float*)d_in[10];
  float* out = (float*)d_out;
  float* ws = (float*)d_ws;

  // workspace layout (floats); total ~104 MB
  float* means = ws + 0;          // 4096
  float* stdev = ws + 4096;       // 4096
  float* x_t   = ws + 8192;       // 4,194,304  (B,C,L) fp32, depth-0 parent + residual
  float* freq  = ws + 4202496;    // 4,194,304  lr fp32; depth-3 parent
  float* IN1   = ws + 8396800;    // 4,194,304  hid_bf; depth-1 parent; dect
  float* IN2   = ws + 12591104;   // 4,194,304  fc weights bf16; depth-2 parent
  float* xeof  = ws + 16785408;   // 4,194,304  freq_bf early; xeo fp32 [p*2+g][B][C][Tn]
  float* wp1f  = ws + 20979712;   // 2,457,600  packed conv w1 bf16
  float* wp2f  = ws + 23437312;   // 2,457,600  packed conv w2 bf16; stats partials early
  float* dect = IN1;
  float* stats_part = wp2f;
  u16* freq_bf = (u16*)xeof;
  u16* hid_bf  = (u16*)IN1;
  u16* fc1w_bf = (u16*)IN2;
  u16* fc2w_bf = (u16*)(IN2 + 1048576);
  u16* wp1 = (u16*)wp1f;
  u16* wp2 = (u16*)wp2f;

  stats1<<<dim3(NB, 16), 256, 0, stream>>>(x_enc, mask, stats_part);
  stats2<<<NB, 128, 0, stream>>>(stats_part, means, stdev);
  norm_transpose<<<dim3(NB, NL / 32, NC / 32), dim3(32, 8), 0, stream>>>(x_enc, mask, means, stdev, x_t);
  haar_kernel<<<NB * NC, 256, 0, stream>>>(x_t, freq_bf);

  cvt2<<<4096, 256, 0, stream>>>(fc1_w, fc2_w, fc1w_bf, fc2w_bf, 524288);
  pack2<<<7680, 256, 0, stream>>>(w1, w2, wp1, wp2);

  // gemm1: 128x128 tiles, grid 16n x 32m; XCD chunk 8m x 8n (cnch=2).
  gemm_n128<<<dim3(16, 32), 256, 0, stream>>>(freq_bf, fc1w_bf, hid_bf,
                                              4096, 2048, 1024, 8, 8);
  // gemm2: 128x64 tiles, grid 16n x 32m; XCD chunk 8m x 8n.
  gemm_mfma<<<dim3(16, 32), 256, 0, stream>>>(hid_bf, fc2w_bf, freq,
                                              4096, 1024, 2048, 8, 8);

  ln_combine<<<4096, 256, 0, stream>>>(freq, x_t, ln_g, ln_b);

  // tree: depth buffers x_t -> IN1 -> IN2 -> freq -> IN1(dect); 2 fused launches per depth
  float* dbuf[5] = {x_t, IN1, IN2, freq, IN1};
  for (int d = 0; d < 4; ++d) {
    int Tn = 512 >> d;
    int nsub = 1 << d;
    dim3 grd(NB, Tn / CT, 2 * nsub);   // 512 blocks at every depth
    ccb_fused<0><<<grd, 256, 0, stream>>>(dbuf[d], xeof, wp1, wp2, b1, b2, d, Tn);
    ccb_fused<1><<<grd, 256, 0, stream>>>(xeof, dbuf[d + 1], wp1, wp2, b1, b2, d, Tn);
  }

  final_kernel<<<dim3(NB, NP), 256, 0, stream>>>(dect, x_t, projw, means, stdev, out);
}

// Round 20
// 340.159 us; speedup vs baseline: 1.1544x; 1.1544x over previous
//
#include <hip/hip_runtime.h>

namespace {

constexpr int NB = 32, NL = 1024, NC = 128, NP = 96, KW = 5;
constexpr float INV_SQRT2 = 0.70710678118654752440f;
constexpr size_t SEG = (size_t)NB * NC;   // 4096
constexpr int CT = 64;                    // output columns per conv block

typedef unsigned short u16;
typedef __attribute__((ext_vector_type(4))) u16 u16x4;
typedef __attribute__((ext_vector_type(8))) u16 u16x8;
typedef __attribute__((ext_vector_type(8))) short short8;
typedef __attribute__((ext_vector_type(4))) float f32x4;

__device__ inline u16 f2bf(float f) {
  unsigned u = __float_as_uint(f);
  u += 0x7fff + ((u >> 16) & 1);
  return (u16)(u >> 16);
}

__device__ inline float ftanh(float x) {
  float e = __expf(2.f * x);
  return 1.f - 2.f / (e + 1.f);
}

// ---------------- stats stage 1 ----------------
__global__ void stats1(const float* __restrict__ x, const float* __restrict__ mask,
                       float* __restrict__ part) {
  int b = blockIdx.x, s = blockIdx.y;
  int tid = threadIdx.x;
  int c = tid & 127, lh = tid >> 7;
  const float* xb = x + (size_t)b * NL * NC;
  const float* mb = mask + (size_t)b * NL * NC;
  float s_all = 0.f, d1 = 0.f, sm = 0.f, sm2 = 0.f, cnz = 0.f;
#pragma unroll 4
  for (int i = 0; i < 32; ++i) {
    int l = s * 64 + lh + 2 * i;
    float v = xb[(size_t)l * NC + c];
    float m = mb[(size_t)l * NC + c];
    s_all += v;
    d1 += (m == 1.f) ? 1.f : 0.f;
    bool nz = (m != 0.f);
    float vm = nz ? v : 0.f;
    sm += vm;
    sm2 += vm * v;
    cnz += nz ? 1.f : 0.f;
  }
  __shared__ float red[5][256];
  red[0][tid] = s_all; red[1][tid] = d1; red[2][tid] = sm;
  red[3][tid] = sm2;   red[4][tid] = cnz;
  __syncthreads();
  if (lh == 0) {
    float* pp = part + ((size_t)(b * 16 + s) * 5) * NC + c;
#pragma unroll
    for (int q = 0; q < 5; ++q) pp[q * NC] = red[q][c] + red[q][c + 128];
  }
}

__global__ void stats2(const float* __restrict__ part, float* __restrict__ means,
                       float* __restrict__ stdev) {
  int b = blockIdx.x, c = threadIdx.x;
  float s_all = 0.f, d1 = 0.f, sm = 0.f, sm2 = 0.f, cnz = 0.f;
  for (int s = 0; s < 16; ++s) {
    const float* pp = part + ((size_t)(b * 16 + s) * 5) * NC + c;
    s_all += pp[0];
    d1    += pp[NC];
    sm    += pp[2 * NC];
    sm2   += pp[3 * NC];
    cnz   += pp[4 * NC];
  }
  float mn = s_all / d1;
  float varsum = sm2 - 2.f * mn * sm + mn * mn * cnz;
  means[b * NC + c] = mn;
  stdev[b * NC + c] = sqrtf(varsum / d1 + 1e-5f);
}

// ---------------- normalize + transpose (B,L,C) -> (B,C,L) ----------------
__global__ void norm_transpose(const float* __restrict__ x, const float* __restrict__ mask,
                               const float* __restrict__ means, const float* __restrict__ stdev,
                               float* __restrict__ xt) {
  __shared__ float tile[32][33];
  int b = blockIdx.x;
  int l0 = blockIdx.y * 32;
  int c0 = blockIdx.z * 32;
  int tx = threadIdx.x;
  int ty = threadIdx.y;
  for (int i = ty; i < 32; i += 8) {
    int l = l0 + i, c = c0 + tx;
    float v = x[((size_t)b * NL + l) * NC + c];
    float m = mask[((size_t)b * NL + l) * NC + c];
    float val = (m == 0.f) ? 0.f : (v - means[b * NC + c]);
    tile[i][tx] = val / stdev[b * NC + c];
  }
  __syncthreads();
  for (int i = ty; i < 32; i += 8) {
    xt[((size_t)b * NC + c0 + i) * NL + l0 + tx] = tile[tx][i];
  }
}

// ---------------- Haar transform per row, bf16 out ----------------
__global__ void haar_kernel(const float* __restrict__ xt, u16* __restrict__ freqb) {
  int row = blockIdx.x;
  __shared__ float h[1024], t2[512];
  const float* src = xt + (size_t)row * NL;
  u16* dst = freqb + (size_t)row * NL;
  for (int i = threadIdx.x; i < 1024; i += 256) h[i] = src[i];
  __syncthreads();
  int n = 1024;
  while (n > 1) {
    int half = n >> 1;
    for (int i = threadIdx.x; i < half; i += 256) {
      float e = h[2 * i], o = h[2 * i + 1];
      dst[half + i] = f2bf((e - o) * INV_SQRT2);
      t2[i] = (e + o) * INV_SQRT2;
    }
    __syncthreads();
    for (int i = threadIdx.x; i < half; i += 256) h[i] = t2[i];
    __syncthreads();
    n = half;
  }
  if (threadIdx.x == 0) dst[0] = f2bf(h[0]);
}

// ---------------- f32 -> bf16, two tensors in one launch ----------------
__global__ void cvt2(const float* __restrict__ in1, const float* __restrict__ in2,
                     u16* __restrict__ o1, u16* __restrict__ o2, int n4) {
  int i = blockIdx.x * 256 + threadIdx.x;
  const float* in = (i < n4) ? in1 : in2;
  u16* op = (i < n4) ? o1 : o2;
  int j = (i < n4) ? i : i - n4;
  if (j < n4) {
    const float4 v = *reinterpret_cast<const float4*>(in + (size_t)j * 4);
    u16x4 o;
    o.x = f2bf(v.x); o.y = f2bf(v.y); o.z = f2bf(v.z); o.w = f2bf(v.w);
    *reinterpret_cast<u16x4*>(op + (size_t)j * 4) = o;
  }
}

// ---------------- pack conv weights into MFMA-fragment order (both sets) ----------------
// dst[n][s=0..19][q=wv*2+mt (0..7)][lane=0..63][j=0..7]:
//   co = (q>>1)*32 + (q&1)*16 + (lane&15); k = s>>2; ci = (s&3)*32 + (lane>>4)*8 + j
//   src = w[n][co][ci][k]  (w layout: [n][co][ci][k], k contiguous)
__global__ void pack2f(const float* __restrict__ w1, const float* __restrict__ w2,
                       u16* __restrict__ wp1, u16* __restrict__ wp2) {
  int idx = blockIdx.x * 256 + threadIdx.x;   // fragment-of-8 index
  const int PERSET = 60 * 20 * 8 * 64;        // 614400
  if (idx >= 2 * PERSET) return;
  const float* w = (idx < PERSET) ? w1 : w2;
  u16* wp = (idx < PERSET) ? wp1 : wp2;
  int r = (idx < PERSET) ? idx : idx - PERSET;
  int n = r / 10240;          // 10240 = 20*8*64
  int r2 = r - n * 10240;
  int s = r2 >> 9;            // /512
  int r3 = r2 & 511;
  int q = r3 >> 6;
  int lane = r3 & 63;
  int co = (q >> 1) * 32 + (q & 1) * 16 + (lane & 15);
  int k = s >> 2;
  int ci0 = (s & 3) * 32 + (lane >> 4) * 8;
  const float* src = w + (((size_t)(n * 128 + co) * 128 + ci0) * 5 + k);
  u16* dst = wp + (size_t)n * 81920 + ((size_t)(s * 8 + q) * 64 + lane) * 8;
#pragma unroll
  for (int j = 0; j < 8; ++j)
    dst[j] = f2bf(src[(size_t)j * 5]);
}

// ---------------- bf16 MFMA GEMM NT, 128m x 128n x 64k, XCD chunk + reg double-buffer ----------------
__global__ __launch_bounds__(256) void gemm_n128(const u16* __restrict__ A,
                                                 const u16* __restrict__ Bw,
                                                 u16* __restrict__ Cb,
                                                 int M, int N, int K, int CM, int CN) {
  __shared__ __align__(16) char sAB[256 * 128];
  int GX = gridDim.x;
  int h = blockIdx.y * GX + blockIdx.x;
  int xcd = h & 7, loc = h >> 3;
  int lm = loc / CN, ln = loc - lm * CN;
  int cnch = GX / CN;
  int m0 = ((xcd / cnch) * CM + lm) * 128;
  int n0 = ((xcd % cnch) * CN + ln) * 128;
  int tid = threadIdx.x;
  int lane = tid & 63, wv = tid >> 6;
  int wm = (wv >> 1) * 64, wn = (wv & 1) * 64;
  int lg = lane >> 4, l15 = lane & 15;

  const u16* srcb[8];
  int swo[8];
#pragma unroll
  for (int pass = 0; pass < 8; ++pass) {
    int o = pass * 4096 + tid * 16;
    int cb = o & 127;
    int row;
    if (pass < 4) {
      row = o >> 7;
      srcb[pass] = A + (size_t)(m0 + row) * K + (cb >> 1);
    } else {
      int rb = (o - 16384) >> 7;
      row = 128 + rb;
      srcb[pass] = Bw + (size_t)(n0 + rb) * K + (cb >> 1);
    }
    swo[pass] = row * 128 + (cb ^ ((row & 7) << 4));
  }

  f32x4 zero = {0.f, 0.f, 0.f, 0.f};
  f32x4 acc[4][4];
#pragma unroll
  for (int i = 0; i < 4; ++i)
#pragma unroll
    for (int j = 0; j < 4; ++j) acc[i][j] = zero;

  u16x8 st[8];
#pragma unroll
  for (int p = 0; p < 8; ++p) st[p] = *(const u16x8*)(srcb[p]);

  for (int k0 = 0; k0 < K; k0 += 64) {
    __syncthreads();
#pragma unroll
    for (int p = 0; p < 8; ++p) *(u16x8*)(sAB + swo[p]) = st[p];
    __syncthreads();
    if (k0 + 64 < K) {
#pragma unroll
      for (int p = 0; p < 8; ++p) st[p] = *(const u16x8*)(srcb[p] + k0 + 64);
    }
#pragma unroll
    for (int ks = 0; ks < 2; ++ks) {
      int kb = ks * 64 + lg * 16;
      short8 a[4], bbf[4];
#pragma unroll
      for (int mt = 0; mt < 4; ++mt) {
        int rr = wm + mt * 16 + l15;
        a[mt] = *(const short8*)(sAB + rr * 128 + (kb ^ ((rr & 7) << 4)));
      }
#pragma unroll
      for (int nt = 0; nt < 4; ++nt) {
        int rr = 128 + wn + nt * 16 + l15;
        bbf[nt] = *(const short8*)(sAB + rr * 128 + (kb ^ ((rr & 7) << 4)));
      }
#pragma unroll
      for (int mt = 0; mt < 4; ++mt)
#pragma unroll
        for (int nt = 0; nt < 4; ++nt)
          acc[mt][nt] = __builtin_amdgcn_mfma_f32_16x16x32_bf16(a[mt], bbf[nt], acc[mt][nt], 0, 0, 0);
    }
  }
#pragma unroll
  for (int mt = 0; mt < 4; ++mt)
#pragma unroll
    for (int nt = 0; nt < 4; ++nt)
#pragma unroll
      for (int r = 0; r < 4; ++r) {
        int row = m0 + wm + mt * 16 + lg * 4 + r;
        int col = n0 + wn + nt * 16 + l15;
        float v = acc[mt][nt][r];
        v = v > 0.f ? v : 0.f;
        Cb[(size_t)row * N + col] = f2bf(v);
      }
}

// ---------------- bf16 MFMA GEMM NT, 128m x 64n x 64k (gemm2: sigmoid -> f32) ----------------
__global__ __launch_bounds__(256) void gemm_mfma(const u16* __restrict__ A,
                                                 const u16* __restrict__ Bw,
                                                 float* __restrict__ Cf,
                                                 int M, int N, int K, int CM, int CN) {
  __shared__ __align__(16) char sAB[(128 + 64) * 128];
  int GX = gridDim.x;
  int h = blockIdx.y * GX + blockIdx.x;
  int xcd = h & 7, loc = h >> 3;
  int lm = loc / CN, ln = loc - lm * CN;
  int cnch = GX / CN;
  int m0 = ((xcd / cnch) * CM + lm) * 128;
  int n0 = ((xcd % cnch) * CN + ln) * 64;
  int tid = threadIdx.x;
  int lane = tid & 63, wv = tid >> 6;
  int wm = (wv >> 1) * 64, wn = (wv & 1) * 32;
  int lg = lane >> 4, l15 = lane & 15;

  const u16* srcb[6];
  int swo[6];
#pragma unroll
  for (int pass = 0; pass < 6; ++pass) {
    int o = pass * 4096 + tid * 16;
    int cb = o & 127;
    int row;
    if (pass < 4) {
      row = o >> 7;
      srcb[pass] = A + (size_t)(m0 + row) * K + (cb >> 1);
    } else {
      int rb = (o - 16384) >> 7;
      row = 128 + rb;
      srcb[pass] = Bw + (size_t)(n0 + rb) * K + (cb >> 1);
    }
    swo[pass] = row * 128 + (cb ^ ((row & 7) << 4));
  }

  f32x4 zero = {0.f, 0.f, 0.f, 0.f};
  f32x4 acc[4][2];
#pragma unroll
  for (int i = 0; i < 4; ++i)
#pragma unroll
    for (int j = 0; j < 2; ++j) acc[i][j] = zero;

  u16x8 st[6];
#pragma unroll
  for (int p = 0; p < 6; ++p) st[p] = *(const u16x8*)(srcb[p]);

  for (int k0 = 0; k0 < K; k0 += 64) {
    __syncthreads();
#pragma unroll
    for (int p = 0; p < 6; ++p) *(u16x8*)(sAB + swo[p]) = st[p];
    __syncthreads();
    if (k0 + 64 < K) {
#pragma unroll
      for (int p = 0; p < 6; ++p) st[p] = *(const u16x8*)(srcb[p] + k0 + 64);
    }
#pragma unroll
    for (int ks = 0; ks < 2; ++ks) {
      int kb = ks * 64 + lg * 16;
      short8 a[4], bbf[2];
#pragma unroll
      for (int mt = 0; mt < 4; ++mt) {
        int rr = wm + mt * 16 + l15;
        a[mt] = *(const short8*)(sAB + rr * 128 + (kb ^ ((rr & 7) << 4)));
      }
#pragma unroll
      for (int nt = 0; nt < 2; ++nt) {
        int rr = 128 + wn + nt * 16 + l15;
        bbf[nt] = *(const short8*)(sAB + rr * 128 + (kb ^ ((rr & 7) << 4)));
      }
#pragma unroll
      for (int mt = 0; mt < 4; ++mt)
#pragma unroll
        for (int nt = 0; nt < 2; ++nt)
          acc[mt][nt] = __builtin_amdgcn_mfma_f32_16x16x32_bf16(a[mt], bbf[nt], acc[mt][nt], 0, 0, 0);
    }
  }
#pragma unroll
  for (int mt = 0; mt < 4; ++mt)
#pragma unroll
    for (int nt = 0; nt < 2; ++nt)
#pragma unroll
      for (int r = 0; r < 4; ++r) {
        int row = m0 + wm + mt * 16 + lg * 4 + r;
        int col = n0 + wn + nt * 16 + l15;
        Cf[(size_t)row * N + col] = 1.f / (1.f + __expf(-acc[mt][nt][r]));
      }
}

// ---------------- fused LayerNorm + combine: xt = xt * LN(lr) + pe ----------------
__global__ void ln_combine(const float* __restrict__ lr, float* __restrict__ xt,
                           const float* __restrict__ g, const float* __restrict__ bta) {
  int row = blockIdx.x;          // b*NC + c
  int c = row & 127;
  const float* p = lr + (size_t)row * 1024;
  int tid = threadIdx.x;
  float v[4];
#pragma unroll
  for (int i = 0; i < 4; ++i) v[i] = p[tid + 256 * i];
  __shared__ float red[256];
  red[tid] = v[0] + v[1] + v[2] + v[3];
  __syncthreads();
  for (int off = 128; off > 0; off >>= 1) {
    if (tid < off) red[tid] += red[tid + off];
    __syncthreads();
  }
  float mu = red[0] * (1.f / 1024.f);
  __syncthreads();
  float sq = 0.f;
#pragma unroll
  for (int i = 0; i < 4; ++i) { float d = v[i] - mu; sq += d * d; }
  red[tid] = sq;
  __syncthreads();
  for (int off = 128; off > 0; off >>= 1) {
    if (tid < off) red[tid] += red[tid + off];
    __syncthreads();
  }
  float rs = rsqrtf(red[0] * (1.f / 1024.f) + 1e-6f);
  int t = c & 63;
  float inv = __expf(-0.14619589f * (float)t);
  float* xr = xt + (size_t)row * 1024;
#pragma unroll
  for (int i = 0; i < 4; ++i) {
    int l = tid + 256 * i;
    float lrv = (v[i] - mu) * rs * g[l] + bta[l];
    float st = (float)l * inv;
    float pe = (c < 64) ? sinf(st) : cosf(st);
    xr[l] = xr[l] * lrv + pe;
  }
}

// ================= fused ccb (conv1 -> leaky -> conv2 -> combine), frag-packed reg weights ======
// VAR 0: ccb0/ccb1 pair (g=z&1): in = parent parity (1-g); out = xeo[p*2+g] = x_par*exp(tanh)
// VAR 1: ccb2/ccb3 pair: in = xeo[p*2 + (g?0:1)]; out = child[2p+g] = xeo[p*2+g] +/- tanh
// sdat row ii = x[t0-8+ii] (clamped); conv1 pos j -> mid_storage[t0-4+j] in smid row j;
// conv2 z[t0+t] reads mid_storage[t0+t+k] = smid row t+k+4.
// Weights frag-packed (pack2f): load = W + (s*8 + wv*2 + mt)*512 + lane*8 (coalesced 1KB/wave).
template <int VAR>
__global__ __launch_bounds__(256) void ccb_fused(
    const float* __restrict__ inF, float* __restrict__ outF,
    const u16* __restrict__ wp1, const u16* __restrict__ wp2,
    const float* __restrict__ b1, const float* __restrict__ b2,
    int d, int Tn) {
  __shared__ __align__(16) char sdat[84 * 256];   // x rows t0-8 .. t0+75 (clamped)
  __shared__ __align__(16) char smid[80 * 256];   // mid_storage[t0-4 .. t0+75]
  int gx = gridDim.x, gy = gridDim.y;
  int total = gx * gy * gridDim.z;
  int hidx = (blockIdx.z * gy + blockIdx.y) * gx + blockIdx.x;
  int lidx = (hidx & 7) * (total >> 3) + (hidx >> 3);
  int b = lidx % gx;
  int rest = lidx / gx;
  int ty = rest % gy;
  int z = rest / gy;
  int p = z >> 1, g = z & 1;
  int node = 0;
  for (int i2 = d - 1; i2 >= 0; --i2) {
    int bit = (p >> i2) & 1;
    int dd = d - 1 - i2;
    node += 1 + bit * ((1 << (3 - dd)) - 1);
  }
  int t0 = CT * ty;
  int tid = threadIdx.x;
  int wq = tid >> 6;
  int lane = tid & 63, wv = wq;
  int lg = lane >> 4, l15 = lane & 15;

  int widx = node * 4 + VAR * 2 + g;
  const u16* W1 = wp1 + (size_t)widx * 81920;
  const u16* W2 = wp2 + (size_t)widx * 81920;
  const float* B1 = b1 + (size_t)widx * 128;
  const float* B2 = b2 + (size_t)widx * 128;
  f32x4 bv1[2], bv2[2];
#pragma unroll
  for (int mt = 0; mt < 2; ++mt) {
    bv1[mt] = *(const f32x4*)(B1 + wv * 32 + mt * 16 + lg * 4);
    bv2[mt] = *(const f32x4*)(B2 + wv * 32 + mt * 16 + lg * 4);
  }

  // frag-packed per-lane weight offset base
  const int wl8 = lane * 8;
  const int wq16 = wv * 2;   // q base = wv*2 + mt

  // ---- issue weight prefetch for steps 0..3 of W1 BEFORE data staging ----
  u16x8 wreg[4][2];
#pragma unroll
  for (int s = 0; s < 4; ++s)
#pragma unroll
    for (int mt = 0; mt < 2; ++mt)
      wreg[s][mt] = *(const u16x8*)(W1 + (size_t)(s * 8 + wq16 + mt) * 512 + wl8);

  // ---- stage x tile: row ii holds x[t0 - 8 + ii], clamped ----
  {
    int i = tid & 63;
#pragma unroll
    for (int rep = 0; rep < 2; ++rep) {
      int ii = i + rep * 64;
      if (ii < 84) {
        int sw0 = (ii & 15) << 4;
        int tt = t0 - 8 + ii;
        tt = tt < 0 ? 0 : (tt >= Tn ? Tn - 1 : tt);
        if (VAR == 0) {
          const float* rp = inF + ((size_t)p * SEG + (size_t)b * NC) * (size_t)(2 * Tn) +
                            2 * tt + (1 - g);
#pragma unroll
          for (int pp = 0; pp < 16; ++pp) {
            int pr = wq * 16 + pp;
            float v0 = rp[(size_t)(2 * pr) * (2 * Tn)];
            float v1 = rp[(size_t)(2 * pr + 1) * (2 * Tn)];
            unsigned pk = (unsigned)f2bf(v0) | ((unsigned)f2bf(v1) << 16);
            *(unsigned*)(sdat + ii * 256 + ((4 * pr) ^ sw0)) = pk;
          }
        } else {
          const float* sp = inF + ((size_t)(p * 2 + (g ? 0 : 1)) * SEG + (size_t)b * NC) * Tn + tt;
#pragma unroll
          for (int pp = 0; pp < 16; ++pp) {
            int pr = wq * 16 + pp;
            unsigned pk = (unsigned)f2bf(sp[(size_t)(2 * pr) * Tn]) |
                          ((unsigned)f2bf(sp[(size_t)(2 * pr + 1) * Tn]) << 16);
            *(unsigned*)(sdat + ii * 256 + ((4 * pr) ^ sw0)) = pk;
          }
        }
      }
    }
  }
  __syncthreads();

  int co_base = wv * 32 + lg * 4;

  // ---- conv1: 20 steps, 5 n-tiles; smid row j = mid_storage[t0-4+j] ----
  f32x4 acc1[2][5];
#pragma unroll
  for (int mt = 0; mt < 2; ++mt)
#pragma unroll
    for (int nt = 0; nt < 5; ++nt) acc1[mt][nt] = bv1[mt];

#pragma unroll
  for (int s = 0; s < 20; ++s) {
    short8 a0 = (short8)wreg[s & 3][0];
    short8 a1 = (short8)wreg[s & 3][1];
    int cbyte = 2 * ((s & 3) * 32 + lg * 8);
    int k = s >> 2;
#pragma unroll
    for (int nt = 0; nt < 5; ++nt) {
      int i = nt * 16 + l15 + k;   // <= 83
      short8 bb = *(const short8*)(sdat + i * 256 + (cbyte ^ ((i & 15) << 4)));
      acc1[0][nt] = __builtin_amdgcn_mfma_f32_16x16x32_bf16(a0, bb, acc1[0][nt], 0, 0, 0);
      acc1[1][nt] = __builtin_amdgcn_mfma_f32_16x16x32_bf16(a1, bb, acc1[1][nt], 0, 0, 0);
    }
    {
      int gs = s + 4;  // global step to prefetch (< 40)
      const u16* W = (gs < 20) ? W1 : W2;
      int ls = (gs < 20) ? gs : gs - 20;
#pragma unroll
      for (int mt = 0; mt < 2; ++mt)
        wreg[s & 3][mt] = *(const u16x8*)(W + (size_t)(ls * 8 + wq16 + mt) * 512 + wl8);
    }
  }

  // ---- leaky + write mid tile ----
#pragma unroll
  for (int mt = 0; mt < 2; ++mt)
#pragma unroll
    for (int nt = 0; nt < 5; ++nt) {
      int j = nt * 16 + l15;
      int co0 = co_base + mt * 16;
      u16x4 m;
#pragma unroll
      for (int r = 0; r < 4; ++r) {
        float v = acc1[mt][nt][r];
        v = v > 0.f ? v : 0.01f * v;
        m[r] = f2bf(v);
      }
      *(u16x4*)(smid + j * 256 + ((2 * co0) ^ ((j & 15) << 4))) = m;
    }
  __syncthreads();   // mid visible to all waves

  // ---- conv2: 20 steps, 4 n-tiles; reads smid row t+k+4 ----
  f32x4 acc2[2][4];
#pragma unroll
  for (int mt = 0; mt < 2; ++mt)
#pragma unroll
    for (int nt = 0; nt < 4; ++nt) acc2[mt][nt] = bv2[mt];

#pragma unroll
  for (int sp = 0; sp < 20; ++sp) {
    short8 a0 = (short8)wreg[sp & 3][0];
    short8 a1 = (short8)wreg[sp & 3][1];
    int cbyte = 2 * ((sp & 3) * 32 + lg * 8);
    int k = sp >> 2;
#pragma unroll
    for (int nt = 0; nt < 4; ++nt) {
      int i = nt * 16 + l15 + k + 4;   // +4: smid row j = mid_storage[t0-4+j]  (<= 71)
      short8 bb = *(const short8*)(smid + i * 256 + (cbyte ^ ((i & 15) << 4)));
      acc2[0][nt] = __builtin_amdgcn_mfma_f32_16x16x32_bf16(a0, bb, acc2[0][nt], 0, 0, 0);
      acc2[1][nt] = __builtin_amdgcn_mfma_f32_16x16x32_bf16(a1, bb, acc2[1][nt], 0, 0, 0);
    }
    if (sp + 4 < 20) {
      int ls = sp + 4;
#pragma unroll
      for (int mt = 0; mt < 2; ++mt)
        wreg[sp & 3][mt] = *(const u16x8*)(W2 + (size_t)(ls * 8 + wq16 + mt) * 512 + wl8);
    }
  }

  // ---- combine + store ----
  if (VAR == 0) {
    const float* par = inF + ((size_t)p * SEG + (size_t)b * NC) * (size_t)(2 * Tn);
    float* xo_ = outF + ((size_t)(p * 2 + g) * SEG + (size_t)b * NC) * Tn;
#pragma unroll
    for (int mt = 0; mt < 2; ++mt)
#pragma unroll
      for (int nt = 0; nt < 4; ++nt) {
        int t = t0 + nt * 16 + l15;
#pragma unroll
        for (int r = 0; r < 4; ++r) {
          int co = co_base + mt * 16 + r;
          float xv = par[(size_t)co * (2 * Tn) + 2 * t + g];   // g0: xe, g1: xo
          xo_[(size_t)co * Tn + t] = xv * __expf(ftanh(acc2[mt][nt][r]));
        }
      }
  } else {
    const float* xf = inF + ((size_t)(p * 2 + g) * SEG + (size_t)b * NC) * Tn;  // g0: xet, g1: xot
    float* ch = outF + ((size_t)(2 * p + g) * SEG + (size_t)b * NC) * Tn;
#pragma unroll
    for (int mt = 0; mt < 2; ++mt)
#pragma unroll
      for (int nt = 0; nt < 4; ++nt) {
        int t = t0 + nt * 16 + l15;
#pragma unroll
        for (int r = 0; r < 4; ++r) {
          int co = co_base + mt * 16 + r;
          float cv = ftanh(acc2[mt][nt][r]);
          float base = xf[(size_t)co * Tn + t];
          ch[(size_t)co * Tn + t] = g ? (base - cv) : (base + cv);
        }
      }
  }
}

// ---------------- final projection + denorm (gathers leaf layout) ----------------
__global__ void final_kernel(const float* __restrict__ dect, const float* __restrict__ xt,
                             const float* __restrict__ projw, const float* __restrict__ means,
                             const float* __restrict__ stdev, float* __restrict__ out) {
  int b = blockIdx.x, p = blockIdx.y;
  int tid = threadIdx.x;
  const float* w = projw + (size_t)(1024 + p) * 1024;
  const float* x0 = xt + (size_t)b * NC * NL;
  float a[3] = {0.f, 0.f, 0.f};
  for (int l = tid; l < 1024; l += 256) {
    float wv = w[l];
    int rl = l & 7;
    int pb = ((rl & 1) << 2) | (rl & 2) | (rl >> 2);
    int br = (l >> 3) & 1;
    int t = l >> 4;
    const float* dl = dect + ((size_t)(2 * pb + br) * NB + b) * NC * 64 + t;
#pragma unroll
    for (int cc = 0; cc < 3; ++cc)
      a[cc] += wv * (dl[(size_t)cc * 64] + x0[(size_t)cc * NL + l]);
  }
  __shared__ float red[3][256];
  for (int cc = 0; cc < 3; ++cc) red[cc][tid] = a[cc];
  __syncthreads();
  for (int off = 128; off > 0; off >>= 1) {
    if (tid < off) {
      red[0][tid] += red[0][tid + off];
      red[1][tid] += red[1][tid + off];
      red[2][tid] += red[2][tid + off];
    }
    __syncthreads();
  }
  if (tid < 3) {
    out[((size_t)b * NP + p) * 3 + tid] = red[tid][0] * stdev[b * NC + tid] + means[b * NC + tid];
  }
}

}  // namespace

extern "C" void kernel_launch(void* const* d_in, const int* in_sizes, int n_in,
                              void* d_out, int out_size, void* d_ws, size_t ws_size,
                              hipStream_t stream) {
  (void)in_sizes; (void)n_in; (void)out_size; (void)ws_size;
  const float* x_enc = (const float*)d_in[0];
  const float* mask  = (const float*)d_in[1];
  const float* fc1_w = (const float*)d_in[2];
  const float* fc2_w = (const float*)d_in[3];
  const float* ln_g  = (const float*)d_in[4];
  const float* ln_b  = (const float*)d_in[5];
  const float* w1    = (const float*)d_in[6];
  const float* b1    = (const float*)d_in[7];
  const float* w2    = (const float*)d_in[8];
  const float* b2    = (const float*)d_in[9];
  const float* projw = (const float*)d_in[10];
  float* out = (float*)d_out;
  float* ws = (float*)d_ws;

  // workspace layout (floats); total ~104 MB
  float* means = ws + 0;          // 4096
  float* stdev = ws + 4096;       // 4096
  float* x_t   = ws + 8192;       // 4,194,304  (B,C,L) fp32, depth-0 parent + residual
  float* freq  = ws + 4202496;    // 4,194,304  lr fp32; depth-3 parent
  float* IN1   = ws + 8396800;    // 4,194,304  hid_bf; depth-1 parent; dect
  float* IN2   = ws + 12591104;   // 4,194,304  fc weights bf16; depth-2 parent
  float* xeof  = ws + 16785408;   // 4,194,304  freq_bf early; xeo fp32 [p*2+g][B][C][Tn]
  float* wp1f  = ws + 20979712;   // 2,457,600  frag-packed conv w1 bf16
  float* wp2f  = ws + 23437312;   // 2,457,600  frag-packed conv w2 bf16; stats partials early
  float* dect = IN1;
  float* stats_part = wp2f;
  u16* freq_bf = (u16*)xeof;
  u16* hid_bf  = (u16*)IN1;
  u16* fc1w_bf = (u16*)IN2;
  u16* fc2w_bf = (u16*)(IN2 + 1048576);
  u16* wp1 = (u16*)wp1f;
  u16* wp2 = (u16*)wp2f;

  stats1<<<dim3(NB, 16), 256, 0, stream>>>(x_enc, mask, stats_part);
  stats2<<<NB, 128, 0, stream>>>(stats_part, means, stdev);
  norm_transpose<<<dim3(NB, NL / 32, NC / 32), dim3(32, 8), 0, stream>>>(x_enc, mask, means, stdev, x_t);
  haar_kernel<<<NB * NC, 256, 0, stream>>>(x_t, freq_bf);

  cvt2<<<4096, 256, 0, stream>>>(fc1_w, fc2_w, fc1w_bf, fc2w_bf, 524288);
  pack2f<<<4800, 256, 0, stream>>>(w1, w2, wp1, wp2);

  // gemm1: 128x128 tiles, grid 16n x 32m; XCD chunk 8m x 8n (cnch=2).
  gemm_n128<<<dim3(16, 32), 256, 0, stream>>>(freq_bf, fc1w_bf, hid_bf,
                                              4096, 2048, 1024, 8, 8);
  // gemm2: 128x64 tiles, grid 16n x 32m; XCD chunk 8m x 8n.
  gemm_mfma<<<dim3(16, 32), 256, 0, stream>>>(hid_bf, fc2w_bf, freq,
                                              4096, 1024, 2048, 8, 8);

  ln_combine<<<4096, 256, 0, stream>>>(freq, x_t, ln_g, ln_b);

  // tree: depth buffers x_t -> IN1 -> IN2 -> freq -> IN1(dect); 2 fused launches per depth
  float* dbuf[5] = {x_t, IN1, IN2, freq, IN1};
  for (int d = 0; d < 4; ++d) {
    int Tn = 512 >> d;
    int nsub = 1 << d;
    dim3 grd(NB, Tn / CT, 2 * nsub);   // 512 blocks at every depth
    ccb_fused<0><<<grd, 256, 0, stream>>>(dbuf[d], xeof, wp1, wp2, b1, b2, d, Tn);
    ccb_fused<1><<<grd, 256, 0, stream>>>(xeof, dbuf[d + 1], wp1, wp2, b1, b2, d, Tn);
  }

  final_kernel<<<dim3(NB, NP), 256, 0, stream>>>(dect, x_t, projw, means, stdev, out);
}

// Round 21
// 327.984 us; speedup vs baseline: 1.1973x; 1.0371x over previous
//
#include <hip/hip_runtime.h>

namespace {

constexpr int NB = 32, NL = 1024, NC = 128, NP = 96, KW = 5;
constexpr float INV_SQRT2 = 0.70710678118654752440f;
constexpr size_t SEG = (size_t)NB * NC;   // 4096
constexpr int CT = 64;                    // output columns per conv block

typedef unsigned short u16;
typedef __attribute__((ext_vector_type(4))) u16 u16x4;
typedef __attribute__((ext_vector_type(8))) u16 u16x8;
typedef __attribute__((ext_vector_type(8))) short short8;
typedef __attribute__((ext_vector_type(4))) float f32x4;

__device__ inline u16 f2bf(float f) {
  unsigned u = __float_as_uint(f);
  u += 0x7fff + ((u >> 16) & 1);
  return (u16)(u >> 16);
}

__device__ inline float ftanh(float x) {
  float e = __expf(2.f * x);
  return 1.f - 2.f / (e + 1.f);
}

// async global->LDS, 16B per lane: lds dest = uniform base + lane*16 (HW), global per-lane
__device__ __forceinline__ void glds16(const void* g, void* l) {
  __builtin_amdgcn_global_load_lds(
      (const __attribute__((address_space(1))) unsigned*)g,
      (__attribute__((address_space(3))) unsigned*)l, 16, 0, 0);
}

// ---------------- stats stage 1 ----------------
__global__ void stats1(const float* __restrict__ x, const float* __restrict__ mask,
                       float* __restrict__ part) {
  int b = blockIdx.x, s = blockIdx.y;
  int tid = threadIdx.x;
  int c = tid & 127, lh = tid >> 7;
  const float* xb = x + (size_t)b * NL * NC;
  const float* mb = mask + (size_t)b * NL * NC;
  float s_all = 0.f, d1 = 0.f, sm = 0.f, sm2 = 0.f, cnz = 0.f;
#pragma unroll 4
  for (int i = 0; i < 32; ++i) {
    int l = s * 64 + lh + 2 * i;
    float v = xb[(size_t)l * NC + c];
    float m = mb[(size_t)l * NC + c];
    s_all += v;
    d1 += (m == 1.f) ? 1.f : 0.f;
    bool nz = (m != 0.f);
    float vm = nz ? v : 0.f;
    sm += vm;
    sm2 += vm * v;
    cnz += nz ? 1.f : 0.f;
  }
  __shared__ float red[5][256];
  red[0][tid] = s_all; red[1][tid] = d1; red[2][tid] = sm;
  red[3][tid] = sm2;   red[4][tid] = cnz;
  __syncthreads();
  if (lh == 0) {
    float* pp = part + ((size_t)(b * 16 + s) * 5) * NC + c;
#pragma unroll
    for (int q = 0; q < 5; ++q) pp[q * NC] = red[q][c] + red[q][c + 128];
  }
}

__global__ void stats2(const float* __restrict__ part, float* __restrict__ means,
                       float* __restrict__ stdev) {
  int b = blockIdx.x, c = threadIdx.x;
  float s_all = 0.f, d1 = 0.f, sm = 0.f, sm2 = 0.f, cnz = 0.f;
  for (int s = 0; s < 16; ++s) {
    const float* pp = part + ((size_t)(b * 16 + s) * 5) * NC + c;
    s_all += pp[0];
    d1    += pp[NC];
    sm    += pp[2 * NC];
    sm2   += pp[3 * NC];
    cnz   += pp[4 * NC];
  }
  float mn = s_all / d1;
  float varsum = sm2 - 2.f * mn * sm + mn * mn * cnz;
  means[b * NC + c] = mn;
  stdev[b * NC + c] = sqrtf(varsum / d1 + 1e-5f);
}

// ---------------- normalize + transpose (B,L,C) -> (B,C,L) ----------------
__global__ void norm_transpose(const float* __restrict__ x, const float* __restrict__ mask,
                               const float* __restrict__ means, const float* __restrict__ stdev,
                               float* __restrict__ xt) {
  __shared__ float tile[32][33];
  int b = blockIdx.x;
  int l0 = blockIdx.y * 32;
  int c0 = blockIdx.z * 32;
  int tx = threadIdx.x;
  int ty = threadIdx.y;
  for (int i = ty; i < 32; i += 8) {
    int l = l0 + i, c = c0 + tx;
    float v = x[((size_t)b * NL + l) * NC + c];
    float m = mask[((size_t)b * NL + l) * NC + c];
    float val = (m == 0.f) ? 0.f : (v - means[b * NC + c]);
    tile[i][tx] = val / stdev[b * NC + c];
  }
  __syncthreads();
  for (int i = ty; i < 32; i += 8) {
    xt[((size_t)b * NC + c0 + i) * NL + l0 + tx] = tile[tx][i];
  }
}

// ---------------- Haar transform per row, bf16 out ----------------
__global__ void haar_kernel(const float* __restrict__ xt, u16* __restrict__ freqb) {
  int row = blockIdx.x;
  __shared__ float h[1024], t2[512];
  const float* src = xt + (size_t)row * NL;
  u16* dst = freqb + (size_t)row * NL;
  for (int i = threadIdx.x; i < 1024; i += 256) h[i] = src[i];
  __syncthreads();
  int n = 1024;
  while (n > 1) {
    int half = n >> 1;
    for (int i = threadIdx.x; i < half; i += 256) {
      float e = h[2 * i], o = h[2 * i + 1];
      dst[half + i] = f2bf((e - o) * INV_SQRT2);
      t2[i] = (e + o) * INV_SQRT2;
    }
    __syncthreads();
    for (int i = threadIdx.x; i < half; i += 256) h[i] = t2[i];
    __syncthreads();
    n = half;
  }
  if (threadIdx.x == 0) dst[0] = f2bf(h[0]);
}

// ---------------- f32 -> bf16, two tensors in one launch ----------------
__global__ void cvt2(const float* __restrict__ in1, const float* __restrict__ in2,
                     u16* __restrict__ o1, u16* __restrict__ o2, int n4) {
  int i = blockIdx.x * 256 + threadIdx.x;
  const float* in = (i < n4) ? in1 : in2;
  u16* op = (i < n4) ? o1 : o2;
  int j = (i < n4) ? i : i - n4;
  if (j < n4) {
    const float4 v = *reinterpret_cast<const float4*>(in + (size_t)j * 4);
    u16x4 o;
    o.x = f2bf(v.x); o.y = f2bf(v.y); o.z = f2bf(v.z); o.w = f2bf(v.w);
    *reinterpret_cast<u16x4*>(op + (size_t)j * 4) = o;
  }
}

// ---------------- pack conv weights [60][co][ci][k] -> [60][k][co][ci] bf16, both sets ----------------
__global__ void pack2(const float* __restrict__ w1, const float* __restrict__ w2,
                      u16* __restrict__ wp1, u16* __restrict__ wp2) {
  int idx = blockIdx.x * 256 + threadIdx.x;
  const int NW = 60 * 128 * 128;
  const float* w = (idx < NW) ? w1 : w2;
  u16* wp = (idx < NW) ? wp1 : wp2;
  int j = (idx < NW) ? idx : idx - NW;
  if (j < NW) {
    int ci = j & 127;
    int co = (j >> 7) & 127;
    int n = j >> 14;
    const float* src = w + (size_t)j * 5;
    size_t base = (size_t)n * (5 * 128 * 128) + (size_t)co * 128 + ci;
#pragma unroll
    for (int k = 0; k < 5; ++k)
      wp[base + (size_t)k * 16384] = f2bf(src[k]);
  }
}

// ---------------- bf16 MFMA GEMM NT, 128m x 128n x 64k, XCD chunk + reg double-buffer ----------------
__global__ __launch_bounds__(256) void gemm_n128(const u16* __restrict__ A,
                                                 const u16* __restrict__ Bw,
                                                 u16* __restrict__ Cb,
                                                 int M, int N, int K, int CM, int CN) {
  __shared__ __align__(16) char sAB[256 * 128];
  int GX = gridDim.x;
  int h = blockIdx.y * GX + blockIdx.x;
  int xcd = h & 7, loc = h >> 3;
  int lm = loc / CN, ln = loc - lm * CN;
  int cnch = GX / CN;
  int m0 = ((xcd / cnch) * CM + lm) * 128;
  int n0 = ((xcd % cnch) * CN + ln) * 128;
  int tid = threadIdx.x;
  int lane = tid & 63, wv = tid >> 6;
  int wm = (wv >> 1) * 64, wn = (wv & 1) * 64;
  int lg = lane >> 4, l15 = lane & 15;

  const u16* srcb[8];
  int swo[8];
#pragma unroll
  for (int pass = 0; pass < 8; ++pass) {
    int o = pass * 4096 + tid * 16;
    int cb = o & 127;
    int row;
    if (pass < 4) {
      row = o >> 7;
      srcb[pass] = A + (size_t)(m0 + row) * K + (cb >> 1);
    } else {
      int rb = (o - 16384) >> 7;
      row = 128 + rb;
      srcb[pass] = Bw + (size_t)(n0 + rb) * K + (cb >> 1);
    }
    swo[pass] = row * 128 + (cb ^ ((row & 7) << 4));
  }

  f32x4 zero = {0.f, 0.f, 0.f, 0.f};
  f32x4 acc[4][4];
#pragma unroll
  for (int i = 0; i < 4; ++i)
#pragma unroll
    for (int j = 0; j < 4; ++j) acc[i][j] = zero;

  u16x8 st[8];
#pragma unroll
  for (int p = 0; p < 8; ++p) st[p] = *(const u16x8*)(srcb[p]);

  for (int k0 = 0; k0 < K; k0 += 64) {
    __syncthreads();
#pragma unroll
    for (int p = 0; p < 8; ++p) *(u16x8*)(sAB + swo[p]) = st[p];
    __syncthreads();
    if (k0 + 64 < K) {
#pragma unroll
      for (int p = 0; p < 8; ++p) st[p] = *(const u16x8*)(srcb[p] + k0 + 64);
    }
#pragma unroll
    for (int ks = 0; ks < 2; ++ks) {
      int kb = ks * 64 + lg * 16;
      short8 a[4], bbf[4];
#pragma unroll
      for (int mt = 0; mt < 4; ++mt) {
        int rr = wm + mt * 16 + l15;
        a[mt] = *(const short8*)(sAB + rr * 128 + (kb ^ ((rr & 7) << 4)));
      }
#pragma unroll
      for (int nt = 0; nt < 4; ++nt) {
        int rr = 128 + wn + nt * 16 + l15;
        bbf[nt] = *(const short8*)(sAB + rr * 128 + (kb ^ ((rr & 7) << 4)));
      }
#pragma unroll
      for (int mt = 0; mt < 4; ++mt)
#pragma unroll
        for (int nt = 0; nt < 4; ++nt)
          acc[mt][nt] = __builtin_amdgcn_mfma_f32_16x16x32_bf16(a[mt], bbf[nt], acc[mt][nt], 0, 0, 0);
    }
  }
#pragma unroll
  for (int mt = 0; mt < 4; ++mt)
#pragma unroll
    for (int nt = 0; nt < 4; ++nt)
#pragma unroll
      for (int r = 0; r < 4; ++r) {
        int row = m0 + wm + mt * 16 + lg * 4 + r;
        int col = n0 + wn + nt * 16 + l15;
        float v = acc[mt][nt][r];
        v = v > 0.f ? v : 0.f;
        Cb[(size_t)row * N + col] = f2bf(v);
      }
}

// ---------------- bf16 MFMA GEMM NT, 128m x 64n x 64k (gemm2: sigmoid -> f32) ----------------
__global__ __launch_bounds__(256) void gemm_mfma(const u16* __restrict__ A,
                                                 const u16* __restrict__ Bw,
                                                 float* __restrict__ Cf,
                                                 int M, int N, int K, int CM, int CN) {
  __shared__ __align__(16) char sAB[(128 + 64) * 128];
  int GX = gridDim.x;
  int h = blockIdx.y * GX + blockIdx.x;
  int xcd = h & 7, loc = h >> 3;
  int lm = loc / CN, ln = loc - lm * CN;
  int cnch = GX / CN;
  int m0 = ((xcd / cnch) * CM + lm) * 128;
  int n0 = ((xcd % cnch) * CN + ln) * 64;
  int tid = threadIdx.x;
  int lane = tid & 63, wv = tid >> 6;
  int wm = (wv >> 1) * 64, wn = (wv & 1) * 32;
  int lg = lane >> 4, l15 = lane & 15;

  const u16* srcb[6];
  int swo[6];
#pragma unroll
  for (int pass = 0; pass < 6; ++pass) {
    int o = pass * 4096 + tid * 16;
    int cb = o & 127;
    int row;
    if (pass < 4) {
      row = o >> 7;
      srcb[pass] = A + (size_t)(m0 + row) * K + (cb >> 1);
    } else {
      int rb = (o - 16384) >> 7;
      row = 128 + rb;
      srcb[pass] = Bw + (size_t)(n0 + rb) * K + (cb >> 1);
    }
    swo[pass] = row * 128 + (cb ^ ((row & 7) << 4));
  }

  f32x4 zero = {0.f, 0.f, 0.f, 0.f};
  f32x4 acc[4][2];
#pragma unroll
  for (int i = 0; i < 4; ++i)
#pragma unroll
    for (int j = 0; j < 2; ++j) acc[i][j] = zero;

  u16x8 st[6];
#pragma unroll
  for (int p = 0; p < 6; ++p) st[p] = *(const u16x8*)(srcb[p]);

  for (int k0 = 0; k0 < K; k0 += 64) {
    __syncthreads();
#pragma unroll
    for (int p = 0; p < 6; ++p) *(u16x8*)(sAB + swo[p]) = st[p];
    __syncthreads();
    if (k0 + 64 < K) {
#pragma unroll
      for (int p = 0; p < 6; ++p) st[p] = *(const u16x8*)(srcb[p] + k0 + 64);
    }
#pragma unroll
    for (int ks = 0; ks < 2; ++ks) {
      int kb = ks * 64 + lg * 16;
      short8 a[4], bbf[2];
#pragma unroll
      for (int mt = 0; mt < 4; ++mt) {
        int rr = wm + mt * 16 + l15;
        a[mt] = *(const short8*)(sAB + rr * 128 + (kb ^ ((rr & 7) << 4)));
      }
#pragma unroll
      for (int nt = 0; nt < 2; ++nt) {
        int rr = 128 + wn + nt * 16 + l15;
        bbf[nt] = *(const short8*)(sAB + rr * 128 + (kb ^ ((rr & 7) << 4)));
      }
#pragma unroll
      for (int mt = 0; mt < 4; ++mt)
#pragma unroll
        for (int nt = 0; nt < 2; ++nt)
          acc[mt][nt] = __builtin_amdgcn_mfma_f32_16x16x32_bf16(a[mt], bbf[nt], acc[mt][nt], 0, 0, 0);
    }
  }
#pragma unroll
  for (int mt = 0; mt < 4; ++mt)
#pragma unroll
    for (int nt = 0; nt < 2; ++nt)
#pragma unroll
      for (int r = 0; r < 4; ++r) {
        int row = m0 + wm + mt * 16 + lg * 4 + r;
        int col = n0 + wn + nt * 16 + l15;
        Cf[(size_t)row * N + col] = 1.f / (1.f + __expf(-acc[mt][nt][r]));
      }
}

// ---------------- fused LayerNorm + combine: xt = xt * LN(lr) + pe ----------------
__global__ void ln_combine(const float* __restrict__ lr, float* __restrict__ xt,
                           const float* __restrict__ g, const float* __restrict__ bta) {
  int row = blockIdx.x;          // b*NC + c
  int c = row & 127;
  const float* p = lr + (size_t)row * 1024;
  int tid = threadIdx.x;
  float v[4];
#pragma unroll
  for (int i = 0; i < 4; ++i) v[i] = p[tid + 256 * i];
  __shared__ float red[256];
  red[tid] = v[0] + v[1] + v[2] + v[3];
  __syncthreads();
  for (int off = 128; off > 0; off >>= 1) {
    if (tid < off) red[tid] += red[tid + off];
    __syncthreads();
  }
  float mu = red[0] * (1.f / 1024.f);
  __syncthreads();
  float sq = 0.f;
#pragma unroll
  for (int i = 0; i < 4; ++i) { float d = v[i] - mu; sq += d * d; }
  red[tid] = sq;
  __syncthreads();
  for (int off = 128; off > 0; off >>= 1) {
    if (tid < off) red[tid] += red[tid + off];
    __syncthreads();
  }
  float rs = rsqrtf(red[0] * (1.f / 1024.f) + 1e-6f);
  int t = c & 63;
  float inv = __expf(-0.14619589f * (float)t);
  float* xr = xt + (size_t)row * 1024;
#pragma unroll
  for (int i = 0; i < 4; ++i) {
    int l = tid + 256 * i;
    float lrv = (v[i] - mu) * rs * g[l] + bta[l];
    float st = (float)l * inv;
    float pe = (c < 64) ? sinf(st) : cosf(st);
    xr[l] = xr[l] * lrv + pe;
  }
}

// ================= fused ccb (conv1 -> leaky -> conv2 -> combine), 8 launches total ======
// VAR 0: ccb0/ccb1 pair (g=z&1): in = parent parity (1-g); out = xeo[p*2+g] = x_par*exp(tanh)
// VAR 1: ccb2/ccb3 pair: in = xeo[p*2 + (g?0:1)]; out = child[2p+g] = xeo[p*2+g] +/- tanh
// sdat row ii = x[t0-8+ii] (clamped); conv1 pos j -> mid_storage[t0-4+j] in smid row j;
// conv2 z[t0+t] reads mid_storage[t0+t+k] = smid row t+k+4.
// Weight pipeline: 40 steps (20 W1, 20 W2), 4 LDS buffers, per-wave 2KB regions, counted vmcnt.
__device__ __forceinline__ void stage_w(const u16* W, char* buf, int wv, int lane, int s) {
  int k = s >> 2, ci0 = (s & 3) * 32;
#pragma unroll
  for (int i = 0; i < 2; ++i) {
    int off = i * 1024 + lane * 16;    // within this wave's 2KB region
    int wl = off >> 7;                 // local co-pair row 0..15
    int wpos = off & 127;
    int u = wpos ^ ((wl & 7) << 4);    // inverse swizzle -> logical position
    int co = wv * 32 + wl * 2 + (u >> 6);
    int ci = ci0 + ((u & 63) >> 1);
    glds16(W + (((size_t)(k * 128 + co)) << 7) + ci, buf + wv * 2048 + i * 1024);
  }
}

template <int VAR>
__global__ __launch_bounds__(256) void ccb_fused(
    const float* __restrict__ inF, float* __restrict__ outF,
    const u16* __restrict__ wp1, const u16* __restrict__ wp2,
    const float* __restrict__ b1, const float* __restrict__ b2,
    int d, int Tn) {
  __shared__ __align__(16) char sdat[84 * 256];   // x rows t0-8 .. t0+75 (clamped)
  __shared__ __align__(16) char smid[80 * 256];   // mid_storage[t0-4 .. t0+75]
  __shared__ __align__(16) char wbuf[4][8192];
  int gx = gridDim.x, gy = gridDim.y;
  int total = gx * gy * gridDim.z;
  int hidx = (blockIdx.z * gy + blockIdx.y) * gx + blockIdx.x;
  int lidx = (hidx & 7) * (total >> 3) + (hidx >> 3);
  int b = lidx % gx;
  int rest = lidx / gx;
  int ty = rest % gy;
  int z = rest / gy;
  int p = z >> 1, g = z & 1;
  int node = 0;
  for (int i2 = d - 1; i2 >= 0; --i2) {
    int bit = (p >> i2) & 1;
    int dd = d - 1 - i2;
    node += 1 + bit * ((1 << (3 - dd)) - 1);
  }
  int t0 = CT * ty;
  int tid = threadIdx.x;
  int wq = tid >> 6;
  int lane = tid & 63, wv = wq;
  int lg = lane >> 4, l15 = lane & 15;

  int widx = node * 4 + VAR * 2 + g;
  const u16* W1 = wp1 + (size_t)widx * (5 * 128 * 128);
  const u16* W2 = wp2 + (size_t)widx * (5 * 128 * 128);
  const float* B1 = b1 + (size_t)widx * 128;
  const float* B2 = b2 + (size_t)widx * 128;
  f32x4 bv1[2], bv2[2];
#pragma unroll
  for (int mt = 0; mt < 2; ++mt) {
    bv1[mt] = *(const f32x4*)(B1 + wv * 32 + mt * 16 + lg * 4);
    bv2[mt] = *(const f32x4*)(B2 + wv * 32 + mt * 16 + lg * 4);
  }

  // ---- stage x tile: row ii holds x[t0 - 8 + ii], clamped ----
  {
    int i = tid & 63;
#pragma unroll
    for (int rep = 0; rep < 2; ++rep) {
      int ii = i + rep * 64;
      if (ii < 84) {
        int sw0 = (ii & 15) << 4;
        int tt = t0 - 8 + ii;
        tt = tt < 0 ? 0 : (tt >= Tn ? Tn - 1 : tt);
        if (VAR == 0) {
          const float* rp = inF + ((size_t)p * SEG + (size_t)b * NC) * (size_t)(2 * Tn) +
                            2 * tt + (1 - g);
#pragma unroll
          for (int pp = 0; pp < 16; ++pp) {
            int pr = wq * 16 + pp;
            float v0 = rp[(size_t)(2 * pr) * (2 * Tn)];
            float v1 = rp[(size_t)(2 * pr + 1) * (2 * Tn)];
            unsigned pk = (unsigned)f2bf(v0) | ((unsigned)f2bf(v1) << 16);
            *(unsigned*)(sdat + ii * 256 + ((4 * pr) ^ sw0)) = pk;
          }
        } else {
          const float* sp = inF + ((size_t)(p * 2 + (g ? 0 : 1)) * SEG + (size_t)b * NC) * Tn + tt;
#pragma unroll
          for (int pp = 0; pp < 16; ++pp) {
            int pr = wq * 16 + pp;
            unsigned pk = (unsigned)f2bf(sp[(size_t)(2 * pr) * Tn]) |
                          ((unsigned)f2bf(sp[(size_t)(2 * pr + 1) * Tn]) << 16);
            *(unsigned*)(sdat + ii * 256 + ((4 * pr) ^ sw0)) = pk;
          }
        }
      }
    }
  }
  // prologue: stage weight steps 0..3 (W1)
  stage_w(W1, wbuf[0], wv, lane, 0);
  stage_w(W1, wbuf[1], wv, lane, 1);
  stage_w(W1, wbuf[2], wv, lane, 2);
  stage_w(W1, wbuf[3], wv, lane, 3);
  __syncthreads();

  int co_base = wv * 32 + lg * 4;

  // ---- conv1: 20 steps, 5 n-tiles; smid row j = mid_storage[t0-4+j] ----
  f32x4 acc1[2][5];
#pragma unroll
  for (int mt = 0; mt < 2; ++mt)
#pragma unroll
    for (int nt = 0; nt < 5; ++nt) acc1[mt][nt] = bv1[mt];

#pragma unroll
  for (int s = 0; s < 20; ++s) {
    asm volatile("s_waitcnt vmcnt(6)" ::: "memory");
    __builtin_amdgcn_sched_barrier(0);
    const char* wb = wbuf[s & 3];
    short8 a[2];
#pragma unroll
    for (int mt = 0; mt < 2; ++mt) {
      int co = wv * 32 + mt * 16 + l15;
      int wrow = co >> 1;
      a[mt] = *(const short8*)(wb + wrow * 128 +
                               ((((co & 1) << 6) | (lg << 4)) ^ ((wrow & 7) << 4)));
    }
    int cbyte = 2 * ((s & 3) * 32 + lg * 8);
    int k = s >> 2;
#pragma unroll
    for (int nt = 0; nt < 5; ++nt) {
      int i = nt * 16 + l15 + k;   // <= 83
      short8 bb = *(const short8*)(sdat + i * 256 + (cbyte ^ ((i & 15) << 4)));
#pragma unroll
      for (int mt = 0; mt < 2; ++mt)
        acc1[mt][nt] = __builtin_amdgcn_mfma_f32_16x16x32_bf16(a[mt], bb, acc1[mt][nt], 0, 0, 0);
    }
    {
      asm volatile("s_waitcnt lgkmcnt(0)" ::: "memory");
      __builtin_amdgcn_sched_barrier(0);
      int gs = s + 4;  // global step to stage (always < 40 here)
      if (gs < 20) stage_w(W1, wbuf[s & 3], wv, lane, gs);
      else         stage_w(W2, wbuf[s & 3], wv, lane, gs - 20);
    }
  }

  // ---- leaky + write mid tile ----
#pragma unroll
  for (int mt = 0; mt < 2; ++mt)
#pragma unroll
    for (int nt = 0; nt < 5; ++nt) {
      int j = nt * 16 + l15;
      int co0 = co_base + mt * 16;
      u16x4 m;
#pragma unroll
      for (int r = 0; r < 4; ++r) {
        float v = acc1[mt][nt][r];
        v = v > 0.f ? v : 0.01f * v;
        m[r] = f2bf(v);
      }
      *(u16x4*)(smid + j * 256 + ((2 * co0) ^ ((j & 15) << 4))) = m;
    }
  __syncthreads();   // mid visible to all waves (drains vmcnt once; W2 prefetches re-land)

  // ---- conv2: 20 steps, 4 n-tiles; reads smid row t+k+4 ----
  f32x4 acc2[2][4];
#pragma unroll
  for (int mt = 0; mt < 2; ++mt)
#pragma unroll
    for (int nt = 0; nt < 4; ++nt) acc2[mt][nt] = bv2[mt];

#pragma unroll
  for (int sp = 0; sp < 20; ++sp) {
    if (sp == 19)      asm volatile("s_waitcnt vmcnt(0)" ::: "memory");
    else if (sp == 18) asm volatile("s_waitcnt vmcnt(2)" ::: "memory");
    else if (sp == 17) asm volatile("s_waitcnt vmcnt(4)" ::: "memory");
    else               asm volatile("s_waitcnt vmcnt(6)" ::: "memory");
    __builtin_amdgcn_sched_barrier(0);
    const char* wb = wbuf[sp & 3];
    short8 a[2];
#pragma unroll
    for (int mt = 0; mt < 2; ++mt) {
      int co = wv * 32 + mt * 16 + l15;
      int wrow = co >> 1;
      a[mt] = *(const short8*)(wb + wrow * 128 +
                               ((((co & 1) << 6) | (lg << 4)) ^ ((wrow & 7) << 4)));
    }
    int cbyte = 2 * ((sp & 3) * 32 + lg * 8);
    int k = sp >> 2;
#pragma unroll
    for (int nt = 0; nt < 4; ++nt) {
      int i = nt * 16 + l15 + k + 4;   // +4: smid row j = mid_storage[t0-4+j]  (<= 71)
      short8 bb = *(const short8*)(smid + i * 256 + (cbyte ^ ((i & 15) << 4)));
#pragma unroll
      for (int mt = 0; mt < 2; ++mt)
        acc2[mt][nt] = __builtin_amdgcn_mfma_f32_16x16x32_bf16(a[mt], bb, acc2[mt][nt], 0, 0, 0);
    }
    if (sp + 4 < 20) {
      asm volatile("s_waitcnt lgkmcnt(0)" ::: "memory");
      __builtin_amdgcn_sched_barrier(0);
      stage_w(W2, wbuf[sp & 3], wv, lane, sp + 4);
    }
  }

  // ---- combine + store ----
  if (VAR == 0) {
    const float* par = inF + ((size_t)p * SEG + (size_t)b * NC) * (size_t)(2 * Tn);
    float* xo_ = outF + ((size_t)(p * 2 + g) * SEG + (size_t)b * NC) * Tn;
#pragma unroll
    for (int mt = 0; mt < 2; ++mt)
#pragma unroll
      for (int nt = 0; nt < 4; ++nt) {
        int t = t0 + nt * 16 + l15;
#pragma unroll
        for (int r = 0; r < 4; ++r) {
          int co = co_base + mt * 16 + r;
          float xv = par[(size_t)co * (2 * Tn) + 2 * t + g];   // g0: xe, g1: xo
          xo_[(size_t)co * Tn + t] = xv * __expf(ftanh(acc2[mt][nt][r]));
        }
      }
  } else {
    const float* xf = inF + ((size_t)(p * 2 + g) * SEG + (size_t)b * NC) * Tn;  // g0: xet, g1: xot
    float* ch = outF + ((size_t)(2 * p + g) * SEG + (size_t)b * NC) * Tn;
#pragma unroll
    for (int mt = 0; mt < 2; ++mt)
#pragma unroll
      for (int nt = 0; nt < 4; ++nt) {
        int t = t0 + nt * 16 + l15;
#pragma unroll
        for (int r = 0; r < 4; ++r) {
          int co = co_base + mt * 16 + r;
          float cv = ftanh(acc2[mt][nt][r]);
          float base = xf[(size_t)co * Tn + t];
          ch[(size_t)co * Tn + t] = g ? (base - cv) : (base + cv);
        }
      }
  }
}

// ---------------- final projection + denorm (gathers leaf layout) ----------------
__global__ void final_kernel(const float* __restrict__ dect, const float* __restrict__ xt,
                             const float* __restrict__ projw, const float* __restrict__ means,
                             const float* __restrict__ stdev, float* __restrict__ out) {
  int b = blockIdx.x, p = blockIdx.y;
  int tid = threadIdx.x;
  const float* w = projw + (size_t)(1024 + p) * 1024;
  const float* x0 = xt + (size_t)b * NC * NL;
  float a[3] = {0.f, 0.f, 0.f};
  for (int l = tid; l < 1024; l += 256) {
    float wv = w[l];
    int rl = l & 7;
    int pb = ((rl & 1) << 2) | (rl & 2) | (rl >> 2);
    int br = (l >> 3) & 1;
    int t = l >> 4;
    const float* dl = dect + ((size_t)(2 * pb + br) * NB + b) * NC * 64 + t;
#pragma unroll
    for (int cc = 0; cc < 3; ++cc)
      a[cc] += wv * (dl[(size_t)cc * 64] + x0[(size_t)cc * NL + l]);
  }
  __shared__ float red[3][256];
  for (int cc = 0; cc < 3; ++cc) red[cc][tid] = a[cc];
  __syncthreads();
  for (int off = 128; off > 0; off >>= 1) {
    if (tid < off) {
      red[0][tid] += red[0][tid + off];
      red[1][tid] += red[1][tid + off];
      red[2][tid] += red[2][tid + off];
    }
    __syncthreads();
  }
  if (tid < 3) {
    out[((size_t)b * NP + p) * 3 + tid] = red[tid][0] * stdev[b * NC + tid] + means[b * NC + tid];
  }
}

}  // namespace

extern "C" void kernel_launch(void* const* d_in, const int* in_sizes, int n_in,
                              void* d_out, int out_size, void* d_ws, size_t ws_size,
                              hipStream_t stream) {
  (void)in_sizes; (void)n_in; (void)out_size; (void)ws_size;
  const float* x_enc = (const float*)d_in[0];
  const float* mask  = (const float*)d_in[1];
  const float* fc1_w = (const float*)d_in[2];
  const float* fc2_w = (const float*)d_in[3];
  const float* ln_g  = (const float*)d_in[4];
  const float* ln_b  = (const float*)d_in[5];
  const float* w1    = (const float*)d_in[6];
  const float* b1    = (const float*)d_in[7];
  const float* w2    = (const float*)d_in[8];
  const float* b2    = (const float*)d_in[9];
  const float* projw = (const float*)d_in[10];
  float* out = (float*)d_out;
  float* ws = (float*)d_ws;

  // workspace layout (floats); total ~104 MB
  float* means = ws + 0;          // 4096
  float* stdev = ws + 4096;       // 4096
  float* x_t   = ws + 8192;       // 4,194,304  (B,C,L) fp32, depth-0 parent + residual
  float* freq  = ws + 4202496;    // 4,194,304  lr fp32; depth-3 parent
  float* IN1   = ws + 8396800;    // 4,194,304  hid_bf; depth-1 parent; dect
  float* IN2   = ws + 12591104;   // 4,194,304  fc weights bf16; depth-2 parent
  float* xeof  = ws + 16785408;   // 4,194,304  freq_bf early; xeo fp32 [p*2+g][B][C][Tn]
  float* wp1f  = ws + 20979712;   // 2,457,600  packed conv w1 bf16
  float* wp2f  = ws + 23437312;   // 2,457,600  packed conv w2 bf16; stats partials early
  float* dect = IN1;
  float* stats_part = wp2f;
  u16* freq_bf = (u16*)xeof;
  u16* hid_bf  = (u16*)IN1;
  u16* fc1w_bf = (u16*)IN2;
  u16* fc2w_bf = (u16*)(IN2 + 1048576);
  u16* wp1 = (u16*)wp1f;
  u16* wp2 = (u16*)wp2f;

  stats1<<<dim3(NB, 16), 256, 0, stream>>>(x_enc, mask, stats_part);
  stats2<<<NB, 128, 0, stream>>>(stats_part, means, stdev);
  norm_transpose<<<dim3(NB, NL / 32, NC / 32), dim3(32, 8), 0, stream>>>(x_enc, mask, means, stdev, x_t);
  haar_kernel<<<NB * NC, 256, 0, stream>>>(x_t, freq_bf);

  cvt2<<<4096, 256, 0, stream>>>(fc1_w, fc2_w, fc1w_bf, fc2w_bf, 524288);
  pack2<<<7680, 256, 0, stream>>>(w1, w2, wp1, wp2);

  // gemm1: 128x128 tiles, grid 16n x 32m; XCD chunk 8m x 8n (cnch=2).
  gemm_n128<<<dim3(16, 32), 256, 0, stream>>>(freq_bf, fc1w_bf, hid_bf,
                                              4096, 2048, 1024, 8, 8);
  // gemm2: 128x64 tiles, grid 16n x 32m; XCD chunk 8m x 8n.
  gemm_mfma<<<dim3(16, 32), 256, 0, stream>>>(hid_bf, fc2w_bf, freq,
                                              4096, 1024, 2048, 8, 8);

  ln_combine<<<4096, 256, 0, stream>>>(freq, x_t, ln_g, ln_b);

  // tree: depth buffers x_t -> IN1 -> IN2 -> freq -> IN1(dect); 2 fused launches per depth
  float* dbuf[5] = {x_t, IN1, IN2, freq, IN1};
  for (int d = 0; d < 4; ++d) {
    int Tn = 512 >> d;
    int nsub = 1 << d;
    dim3 grd(NB, Tn / CT, 2 * nsub);   // 512 blocks at every depth
    ccb_fused<0><<<grd, 256, 0, stream>>>(dbuf[d], xeof, wp1, wp2, b1, b2, d, Tn);
    ccb_fused<1><<<grd, 256, 0, stream>>>(xeof, dbuf[d + 1], wp1, wp2, b1, b2, d, Tn);
  }

  final_kernel<<<dim3(NB, NP), 256, 0, stream>>>(dect, x_t, projw, means, stdev, out);
}

// Round 23
// 323.602 us; speedup vs baseline: 1.2135x; 1.0135x over previous
//
#include <hip/hip_runtime.h>

namespace {

constexpr int NB = 32, NL = 1024, NC = 128, NP = 96, KW = 5;
constexpr float INV_SQRT2 = 0.70710678118654752440f;
constexpr size_t SEG = (size_t)NB * NC;   // 4096
constexpr int CT = 64;                    // output columns per conv block

typedef unsigned short u16;
typedef __attribute__((ext_vector_type(4))) u16 u16x4;
typedef __attribute__((ext_vector_type(8))) u16 u16x8;
typedef __attribute__((ext_vector_type(8))) short short8;
typedef __attribute__((ext_vector_type(4))) float f32x4;

__device__ inline u16 f2bf(float f) {
  unsigned u = __float_as_uint(f);
  u += 0x7fff + ((u >> 16) & 1);
  return (u16)(u >> 16);
}

__device__ inline float ftanh(float x) {
  float e = __expf(2.f * x);
  return 1.f - 2.f / (e + 1.f);
}

// async global->LDS, 16B per lane: lds dest = uniform base + lane*16 (HW), global per-lane
__device__ __forceinline__ void glds16(const void* g, void* l) {
  __builtin_amdgcn_global_load_lds(
      (const __attribute__((address_space(1))) unsigned*)g,
      (__attribute__((address_space(3))) unsigned*)l, 16, 0, 0);
}

// ---------------- stats stage 1 ----------------
__global__ void stats1(const float* __restrict__ x, const float* __restrict__ mask,
                       float* __restrict__ part) {
  int b = blockIdx.x, s = blockIdx.y;
  int tid = threadIdx.x;
  int c = tid & 127, lh = tid >> 7;
  const float* xb = x + (size_t)b * NL * NC;
  const float* mb = mask + (size_t)b * NL * NC;
  float s_all = 0.f, d1 = 0.f, sm = 0.f, sm2 = 0.f, cnz = 0.f;
#pragma unroll 4
  for (int i = 0; i < 32; ++i) {
    int l = s * 64 + lh + 2 * i;
    float v = xb[(size_t)l * NC + c];
    float m = mb[(size_t)l * NC + c];
    s_all += v;
    d1 += (m == 1.f) ? 1.f : 0.f;
    bool nz = (m != 0.f);
    float vm = nz ? v : 0.f;
    sm += vm;
    sm2 += vm * v;
    cnz += nz ? 1.f : 0.f;
  }
  __shared__ float red[5][256];
  red[0][tid] = s_all; red[1][tid] = d1; red[2][tid] = sm;
  red[3][tid] = sm2;   red[4][tid] = cnz;
  __syncthreads();
  if (lh == 0) {
    float* pp = part + ((size_t)(b * 16 + s) * 5) * NC + c;
#pragma unroll
    for (int q = 0; q < 5; ++q) pp[q * NC] = red[q][c] + red[q][c + 128];
  }
}

// ---------------- normalize + transpose (B,L,C) -> (B,C,L); folds stats2 ----------------
__global__ void norm_transpose(const float* __restrict__ x, const float* __restrict__ mask,
                               const float* __restrict__ part,
                               float* __restrict__ means, float* __restrict__ stdev,
                               float* __restrict__ xt) {
  __shared__ float tile[32][33];
  __shared__ float smean[32], sstd[32];
  int b = blockIdx.x;
  int l0 = blockIdx.y * 32;
  int c0 = blockIdx.z * 32;
  int tx = threadIdx.x;
  int ty = threadIdx.y;
  if (ty == 0) {
    int c = c0 + tx;
    float s_all = 0.f, d1 = 0.f, sm = 0.f, sm2 = 0.f, cnz = 0.f;
    for (int s = 0; s < 16; ++s) {
      const float* pp = part + ((size_t)(b * 16 + s) * 5) * NC + c;
      s_all += pp[0];
      d1    += pp[NC];
      sm    += pp[2 * NC];
      sm2   += pp[3 * NC];
      cnz   += pp[4 * NC];
    }
    float mn = s_all / d1;
    float varsum = sm2 - 2.f * mn * sm + mn * mn * cnz;
    float sd = sqrtf(varsum / d1 + 1e-5f);
    smean[tx] = mn; sstd[tx] = sd;
    if (blockIdx.y == 0) { means[b * NC + c] = mn; stdev[b * NC + c] = sd; }
  }
  __syncthreads();
  for (int i = ty; i < 32; i += 8) {
    int l = l0 + i, c = c0 + tx;
    float v = x[((size_t)b * NL + l) * NC + c];
    float m = mask[((size_t)b * NL + l) * NC + c];
    float val = (m == 0.f) ? 0.f : (v - smean[tx]);
    tile[i][tx] = val / sstd[tx];
  }
  __syncthreads();
  for (int i = ty; i < 32; i += 8) {
    xt[((size_t)b * NC + c0 + i) * NL + l0 + tx] = tile[tx][i];
  }
}

// ---------------- merged prep: haar rows | fc-weight cvt | conv-weight pack ----------------
__global__ void prep3(const float* __restrict__ xt, u16* __restrict__ freqb,
                      const float* __restrict__ fc1_w, const float* __restrict__ fc2_w,
                      u16* __restrict__ o1, u16* __restrict__ o2,
                      const float* __restrict__ w1, const float* __restrict__ w2,
                      u16* __restrict__ wp1, u16* __restrict__ wp2) {
  int bid = blockIdx.x;
  int tid = threadIdx.x;
  if (bid < 4096) {
    // ---- Haar transform per row, bf16 out ----
    __shared__ float h[1024], t2[512];
    int row = bid;
    const float* src = xt + (size_t)row * NL;
    u16* dst = freqb + (size_t)row * NL;
    for (int i = tid; i < 1024; i += 256) h[i] = src[i];
    __syncthreads();
    int n = 1024;
    while (n > 1) {
      int half = n >> 1;
      for (int i = tid; i < half; i += 256) {
        float e = h[2 * i], o = h[2 * i + 1];
        dst[half + i] = f2bf((e - o) * INV_SQRT2);
        t2[i] = (e + o) * INV_SQRT2;
      }
      __syncthreads();
      for (int i = tid; i < half; i += 256) h[i] = t2[i];
      __syncthreads();
      n = half;
    }
    if (tid == 0) dst[0] = f2bf(h[0]);
  } else if (bid < 8192) {
    // ---- f32 -> bf16 for both fc weights ----
    const int n4 = 524288;
    int i = (bid - 4096) * 256 + tid;
    const float* in = (i < n4) ? fc1_w : fc2_w;
    u16* op = (i < n4) ? o1 : o2;
    int j = (i < n4) ? i : i - n4;
    const float4 v = *reinterpret_cast<const float4*>(in + (size_t)j * 4);
    u16x4 o;
    o.x = f2bf(v.x); o.y = f2bf(v.y); o.z = f2bf(v.z); o.w = f2bf(v.w);
    *reinterpret_cast<u16x4*>(op + (size_t)j * 4) = o;
  } else {
    // ---- pack conv weights [60][co][ci][k] -> [60][k][co][ci] bf16, both sets ----
    int idx = (bid - 8192) * 256 + tid;
    const int NW = 60 * 128 * 128;
    const float* w = (idx < NW) ? w1 : w2;
    u16* wp = (idx < NW) ? wp1 : wp2;
    int j = (idx < NW) ? idx : idx - NW;
    if (j < NW) {
      int ci = j & 127;
      int co = (j >> 7) & 127;
      int n = j >> 14;
      const float* src = w + (size_t)j * 5;
      size_t base = (size_t)n * (5 * 128 * 128) + (size_t)co * 128 + ci;
#pragma unroll
      for (int k = 0; k < 5; ++k)
        wp[base + (size_t)k * 16384] = f2bf(src[k]);
    }
  }
}

// ---------------- bf16 MFMA GEMM NT, 128m x 128n x 64k, XCD chunk + reg double-buffer ----------------
__global__ __launch_bounds__(256) void gemm_n128(const u16* __restrict__ A,
                                                 const u16* __restrict__ Bw,
                                                 u16* __restrict__ Cb,
                                                 int M, int N, int K, int CM, int CN) {
  __shared__ __align__(16) char sAB[256 * 128];
  int GX = gridDim.x;
  int h = blockIdx.y * GX + blockIdx.x;
  int xcd = h & 7, loc = h >> 3;
  int lm = loc / CN, ln = loc - lm * CN;
  int cnch = GX / CN;
  int m0 = ((xcd / cnch) * CM + lm) * 128;
  int n0 = ((xcd % cnch) * CN + ln) * 128;
  int tid = threadIdx.x;
  int lane = tid & 63, wv = tid >> 6;
  int wm = (wv >> 1) * 64, wn = (wv & 1) * 64;
  int lg = lane >> 4, l15 = lane & 15;

  const u16* srcb[8];
  int swo[8];
#pragma unroll
  for (int pass = 0; pass < 8; ++pass) {
    int o = pass * 4096 + tid * 16;
    int cb = o & 127;
    int row;
    if (pass < 4) {
      row = o >> 7;
      srcb[pass] = A + (size_t)(m0 + row) * K + (cb >> 1);
    } else {
      int rb = (o - 16384) >> 7;
      row = 128 + rb;
      srcb[pass] = Bw + (size_t)(n0 + rb) * K + (cb >> 1);
    }
    swo[pass] = row * 128 + (cb ^ ((row & 7) << 4));
  }

  f32x4 zero = {0.f, 0.f, 0.f, 0.f};
  f32x4 acc[4][4];
#pragma unroll
  for (int i = 0; i < 4; ++i)
#pragma unroll
    for (int j = 0; j < 4; ++j) acc[i][j] = zero;

  u16x8 st[8];
#pragma unroll
  for (int p = 0; p < 8; ++p) st[p] = *(const u16x8*)(srcb[p]);

  for (int k0 = 0; k0 < K; k0 += 64) {
    __syncthreads();
#pragma unroll
    for (int p = 0; p < 8; ++p) *(u16x8*)(sAB + swo[p]) = st[p];
    __syncthreads();
    if (k0 + 64 < K) {
#pragma unroll
      for (int p = 0; p < 8; ++p) st[p] = *(const u16x8*)(srcb[p] + k0 + 64);
    }
#pragma unroll
    for (int ks = 0; ks < 2; ++ks) {
      int kb = ks * 64 + lg * 16;
      short8 a[4], bbf[4];
#pragma unroll
      for (int mt = 0; mt < 4; ++mt) {
        int rr = wm + mt * 16 + l15;
        a[mt] = *(const short8*)(sAB + rr * 128 + (kb ^ ((rr & 7) << 4)));
      }
#pragma unroll
      for (int nt = 0; nt < 4; ++nt) {
        int rr = 128 + wn + nt * 16 + l15;
        bbf[nt] = *(const short8*)(sAB + rr * 128 + (kb ^ ((rr & 7) << 4)));
      }
#pragma unroll
      for (int mt = 0; mt < 4; ++mt)
#pragma unroll
        for (int nt = 0; nt < 4; ++nt)
          acc[mt][nt] = __builtin_amdgcn_mfma_f32_16x16x32_bf16(a[mt], bbf[nt], acc[mt][nt], 0, 0, 0);
    }
  }
#pragma unroll
  for (int mt = 0; mt < 4; ++mt)
#pragma unroll
    for (int nt = 0; nt < 4; ++nt)
#pragma unroll
      for (int r = 0; r < 4; ++r) {
        int row = m0 + wm + mt * 16 + lg * 4 + r;
        int col = n0 + wn + nt * 16 + l15;
        float v = acc[mt][nt][r];
        v = v > 0.f ? v : 0.f;
        Cb[(size_t)row * N + col] = f2bf(v);
      }
}

// ---------------- bf16 MFMA GEMM NT, 128m x 64n x 64k (gemm2: sigmoid -> f32) ----------------
__global__ __launch_bounds__(256) void gemm_mfma(const u16* __restrict__ A,
                                                 const u16* __restrict__ Bw,
                                                 float* __restrict__ Cf,
                                                 int M, int N, int K, int CM, int CN) {
  __shared__ __align__(16) char sAB[(128 + 64) * 128];
  int GX = gridDim.x;
  int h = blockIdx.y * GX + blockIdx.x;
  int xcd = h & 7, loc = h >> 3;
  int lm = loc / CN, ln = loc - lm * CN;
  int cnch = GX / CN;
  int m0 = ((xcd / cnch) * CM + lm) * 128;
  int n0 = ((xcd % cnch) * CN + ln) * 64;
  int tid = threadIdx.x;
  int lane = tid & 63, wv = tid >> 6;
  int wm = (wv >> 1) * 64, wn = (wv & 1) * 32;
  int lg = lane >> 4, l15 = lane & 15;

  const u16* srcb[6];
  int swo[6];
#pragma unroll
  for (int pass = 0; pass < 6; ++pass) {
    int o = pass * 4096 + tid * 16;
    int cb = o & 127;
    int row;
    if (pass < 4) {
      row = o >> 7;
      srcb[pass] = A + (size_t)(m0 + row) * K + (cb >> 1);
    } else {
      int rb = (o - 16384) >> 7;
      row = 128 + rb;
      srcb[pass] = Bw + (size_t)(n0 + rb) * K + (cb >> 1);
    }
    swo[pass] = row * 128 + (cb ^ ((row & 7) << 4));
  }

  f32x4 zero = {0.f, 0.f, 0.f, 0.f};
  f32x4 acc[4][2];
#pragma unroll
  for (int i = 0; i < 4; ++i)
#pragma unroll
    for (int j = 0; j < 2; ++j) acc[i][j] = zero;

  u16x8 st[6];
#pragma unroll
  for (int p = 0; p < 6; ++p) st[p] = *(const u16x8*)(srcb[p]);

  for (int k0 = 0; k0 < K; k0 += 64) {
    __syncthreads();
#pragma unroll
    for (int p = 0; p < 6; ++p) *(u16x8*)(sAB + swo[p]) = st[p];
    __syncthreads();
    if (k0 + 64 < K) {
#pragma unroll
      for (int p = 0; p < 6; ++p) st[p] = *(const u16x8*)(srcb[p] + k0 + 64);
    }
#pragma unroll
    for (int ks = 0; ks < 2; ++ks) {
      int kb = ks * 64 + lg * 16;
      short8 a[4], bbf[2];
#pragma unroll
      for (int mt = 0; mt < 4; ++mt) {
        int rr = wm + mt * 16 + l15;
        a[mt] = *(const short8*)(sAB + rr * 128 + (kb ^ ((rr & 7) << 4)));
      }
#pragma unroll
      for (int nt = 0; nt < 2; ++nt) {
        int rr = 128 + wn + nt * 16 + l15;
        bbf[nt] = *(const short8*)(sAB + rr * 128 + (kb ^ ((rr & 7) << 4)));
      }
#pragma unroll
      for (int mt = 0; mt < 4; ++mt)
#pragma unroll
        for (int nt = 0; nt < 2; ++nt)
          acc[mt][nt] = __builtin_amdgcn_mfma_f32_16x16x32_bf16(a[mt], bbf[nt], acc[mt][nt], 0, 0, 0);
    }
  }
#pragma unroll
  for (int mt = 0; mt < 4; ++mt)
#pragma unroll
    for (int nt = 0; nt < 2; ++nt)
#pragma unroll
      for (int r = 0; r < 4; ++r) {
        int row = m0 + wm + mt * 16 + lg * 4 + r;
        int col = n0 + wn + nt * 16 + l15;
        Cf[(size_t)row * N + col] = 1.f / (1.f + __expf(-acc[mt][nt][r]));
      }
}

// ---------------- fused LayerNorm + combine: xt = xt * LN(lr) + pe ----------------
__global__ void ln_combine(const float* __restrict__ lr, float* __restrict__ xt,
                           const float* __restrict__ g, const float* __restrict__ bta) {
  int row = blockIdx.x;          // b*NC + c
  int c = row & 127;
  const float* p = lr + (size_t)row * 1024;
  int tid = threadIdx.x;
  float v[4];
#pragma unroll
  for (int i = 0; i < 4; ++i) v[i] = p[tid + 256 * i];
  __shared__ float red[256];
  red[tid] = v[0] + v[1] + v[2] + v[3];
  __syncthreads();
  for (int off = 128; off > 0; off >>= 1) {
    if (tid < off) red[tid] += red[tid + off];
    __syncthreads();
  }
  float mu = red[0] * (1.f / 1024.f);
  __syncthreads();
  float sq = 0.f;
#pragma unroll
  for (int i = 0; i < 4; ++i) { float d = v[i] - mu; sq += d * d; }
  red[tid] = sq;
  __syncthreads();
  for (int off = 128; off > 0; off >>= 1) {
    if (tid < off) red[tid] += red[tid + off];
    __syncthreads();
  }
  float rs = rsqrtf(red[0] * (1.f / 1024.f) + 1e-6f);
  int t = c & 63;
  float inv = __expf(-0.14619589f * (float)t);
  float* xr = xt + (size_t)row * 1024;
#pragma unroll
  for (int i = 0; i < 4; ++i) {
    int l = tid + 256 * i;
    float lrv = (v[i] - mu) * rs * g[l] + bta[l];
    float st = (float)l * inv;
    float pe = (c < 64) ? sinf(st) : cosf(st);
    xr[l] = xr[l] * lrv + pe;
  }
}

// ================= fused ccb (conv1 -> leaky -> conv2 -> combine), 8 launches total ======
// VAR 0: ccb0/ccb1 pair (g=z&1): in = parent parity (1-g); out = xeo[p*2+g] = x_par*exp(tanh)
// VAR 1: ccb2/ccb3 pair: in = xeo[p*2 + (g?0:1)]; out = child[2p+g] = xeo[p*2+g] +/- tanh
// sdat row ii = x[t0-8+ii] (clamped); conv1 pos j -> mid_storage[t0-4+j] in smid row j;
// conv2 z[t0+t] reads mid_storage[t0+t+k] = smid row t+k+4.
// Weight pipeline: 40 steps (20 W1, 20 W2), 4 LDS buffers, per-wave 2KB regions, counted vmcnt.
__device__ __forceinline__ void stage_w(const u16* W, char* buf, int wv, int lane, int s) {
  int k = s >> 2, ci0 = (s & 3) * 32;
#pragma unroll
  for (int i = 0; i < 2; ++i) {
    int off = i * 1024 + lane * 16;    // within this wave's 2KB region
    int wl = off >> 7;                 // local co-pair row 0..15
    int wpos = off & 127;
    int u = wpos ^ ((wl & 7) << 4);    // inverse swizzle -> logical position
    int co = wv * 32 + wl * 2 + (u >> 6);
    int ci = ci0 + ((u & 63) >> 1);
    glds16(W + (((size_t)(k * 128 + co)) << 7) + ci, buf + wv * 2048 + i * 1024);
  }
}

template <int VAR>
__global__ __launch_bounds__(256) void ccb_fused(
    const float* __restrict__ inF, float* __restrict__ outF,
    const u16* __restrict__ wp1, const u16* __restrict__ wp2,
    const float* __restrict__ b1, const float* __restrict__ b2,
    int d, int Tn) {
  __shared__ __align__(16) char sdat[84 * 256];   // x rows t0-8 .. t0+75 (clamped)
  __shared__ __align__(16) char smid[80 * 256];   // mid_storage[t0-4 .. t0+75]
  __shared__ __align__(16) char wbuf[4][8192];
  int gx = gridDim.x, gy = gridDim.y;
  int total = gx * gy * gridDim.z;
  int hidx = (blockIdx.z * gy + blockIdx.y) * gx + blockIdx.x;
  int lidx = (hidx & 7) * (total >> 3) + (hidx >> 3);
  int b = lidx % gx;
  int rest = lidx / gx;
  int ty = rest % gy;
  int z = rest / gy;
  int p = z >> 1, g = z & 1;
  int node = 0;
  for (int i2 = d - 1; i2 >= 0; --i2) {
    int bit = (p >> i2) & 1;
    int dd = d - 1 - i2;
    node += 1 + bit * ((1 << (3 - dd)) - 1);
  }
  int t0 = CT * ty;
  int tid = threadIdx.x;
  int wq = tid >> 6;
  int lane = tid & 63, wv = wq;
  int lg = lane >> 4, l15 = lane & 15;

  int widx = node * 4 + VAR * 2 + g;
  const u16* W1 = wp1 + (size_t)widx * (5 * 128 * 128);
  const u16* W2 = wp2 + (size_t)widx * (5 * 128 * 128);
  const float* B1 = b1 + (size_t)widx * 128;
  const float* B2 = b2 + (size_t)widx * 128;
  f32x4 bv1[2], bv2[2];
#pragma unroll
  for (int mt = 0; mt < 2; ++mt) {
    bv1[mt] = *(const f32x4*)(B1 + wv * 32 + mt * 16 + lg * 4);
    bv2[mt] = *(const f32x4*)(B2 + wv * 32 + mt * 16 + lg * 4);
  }

  // ---- stage x tile: row ii holds x[t0 - 8 + ii], clamped ----
  {
    int i = tid & 63;
#pragma unroll
    for (int rep = 0; rep < 2; ++rep) {
      int ii = i + rep * 64;
      if (ii < 84) {
        int sw0 = (ii & 15) << 4;
        int tt = t0 - 8 + ii;
        tt = tt < 0 ? 0 : (tt >= Tn ? Tn - 1 : tt);
        if (VAR == 0) {
          const float* rp = inF + ((size_t)p * SEG + (size_t)b * NC) * (size_t)(2 * Tn) +
                            2 * tt + (1 - g);
#pragma unroll
          for (int pp = 0; pp < 16; ++pp) {
            int pr = wq * 16 + pp;
            float v0 = rp[(size_t)(2 * pr) * (2 * Tn)];
            float v1 = rp[(size_t)(2 * pr + 1) * (2 * Tn)];
            unsigned pk = (unsigned)f2bf(v0) | ((unsigned)f2bf(v1) << 16);
            *(unsigned*)(sdat + ii * 256 + ((4 * pr) ^ sw0)) = pk;
          }
        } else {
          const float* sp = inF + ((size_t)(p * 2 + (g ? 0 : 1)) * SEG + (size_t)b * NC) * Tn + tt;
#pragma unroll
          for (int pp = 0; pp < 16; ++pp) {
            int pr = wq * 16 + pp;
            unsigned pk = (unsigned)f2bf(sp[(size_t)(2 * pr) * Tn]) |
                          ((unsigned)f2bf(sp[(size_t)(2 * pr + 1) * Tn]) << 16);
            *(unsigned*)(sdat + ii * 256 + ((4 * pr) ^ sw0)) = pk;
          }
        }
      }
    }
  }
  // prologue: stage weight steps 0..3 (W1)
  stage_w(W1, wbuf[0], wv, lane, 0);
  stage_w(W1, wbuf[1], wv, lane, 1);
  stage_w(W1, wbuf[2], wv, lane, 2);
  stage_w(W1, wbuf[3], wv, lane, 3);
  __syncthreads();

  int co_base = wv * 32 + lg * 4;

  // ---- conv1: 20 steps, 5 n-tiles; smid row j = mid_storage[t0-4+j] ----
  f32x4 acc1[2][5];
#pragma unroll
  for (int mt = 0; mt < 2; ++mt)
#pragma unroll
    for (int nt = 0; nt < 5; ++nt) acc1[mt][nt] = bv1[mt];

#pragma unroll
  for (int s = 0; s < 20; ++s) {
    asm volatile("s_waitcnt vmcnt(6)" ::: "memory");
    __builtin_amdgcn_sched_barrier(0);
    const char* wb = wbuf[s & 3];
    short8 a[2];
#pragma unroll
    for (int mt = 0; mt < 2; ++mt) {
      int co = wv * 32 + mt * 16 + l15;
      int wrow = co >> 1;
      a[mt] = *(const short8*)(wb + wrow * 128 +
                               ((((co & 1) << 6) | (lg << 4)) ^ ((wrow & 7) << 4)));
    }
    int cbyte = 2 * ((s & 3) * 32 + lg * 8);
    int k = s >> 2;
#pragma unroll
    for (int nt = 0; nt < 5; ++nt) {
      int i = nt * 16 + l15 + k;   // <= 83
      short8 bb = *(const short8*)(sdat + i * 256 + (cbyte ^ ((i & 15) << 4)));
#pragma unroll
      for (int mt = 0; mt < 2; ++mt)
        acc1[mt][nt] = __builtin_amdgcn_mfma_f32_16x16x32_bf16(a[mt], bb, acc1[mt][nt], 0, 0, 0);
    }
    {
      asm volatile("s_waitcnt lgkmcnt(0)" ::: "memory");
      __builtin_amdgcn_sched_barrier(0);
      int gs = s + 4;  // global step to stage (always < 40 here)
      if (gs < 20) stage_w(W1, wbuf[s & 3], wv, lane, gs);
      else         stage_w(W2, wbuf[s & 3], wv, lane, gs - 20);
    }
  }

  // ---- leaky + write mid tile ----
#pragma unroll
  for (int mt = 0; mt < 2; ++mt)
#pragma unroll
    for (int nt = 0; nt < 5; ++nt) {
      int j = nt * 16 + l15;
      int co0 = co_base + mt * 16;
      u16x4 m;
#pragma unroll
      for (int r = 0; r < 4; ++r) {
        float v = acc1[mt][nt][r];
        v = v > 0.f ? v : 0.01f * v;
        m[r] = f2bf(v);
      }
      *(u16x4*)(smid + j * 256 + ((2 * co0) ^ ((j & 15) << 4))) = m;
    }
  __syncthreads();   // mid visible to all waves (drains vmcnt once; W2 prefetches re-land)

  // ---- conv2: 20 steps, 4 n-tiles; reads smid row t+k+4 ----
  f32x4 acc2[2][4];
#pragma unroll
  for (int mt = 0; mt < 2; ++mt)
#pragma unroll
    for (int nt = 0; nt < 4; ++nt) acc2[mt][nt] = bv2[mt];

#pragma unroll
  for (int sp = 0; sp < 20; ++sp) {
    if (sp == 19)      asm volatile("s_waitcnt vmcnt(0)" ::: "memory");
    else if (sp == 18) asm volatile("s_waitcnt vmcnt(2)" ::: "memory");
    else if (sp == 17) asm volatile("s_waitcnt vmcnt(4)" ::: "memory");
    else               asm volatile("s_waitcnt vmcnt(6)" ::: "memory");
    __builtin_amdgcn_sched_barrier(0);
    const char* wb = wbuf[sp & 3];
    short8 a[2];
#pragma unroll
    for (int mt = 0; mt < 2; ++mt) {
      int co = wv * 32 + mt * 16 + l15;
      int wrow = co >> 1;
      a[mt] = *(const short8*)(wb + wrow * 128 +
                               ((((co & 1) << 6) | (lg << 4)) ^ ((wrow & 7) << 4)));
    }
    int cbyte = 2 * ((sp & 3) * 32 + lg * 8);
    int k = sp >> 2;
#pragma unroll
    for (int nt = 0; nt < 4; ++nt) {
      int i = nt * 16 + l15 + k + 4;   // +4: smid row j = mid_storage[t0-4+j]  (<= 71)
      short8 bb = *(const short8*)(smid + i * 256 + (cbyte ^ ((i & 15) << 4)));
#pragma unroll
      for (int mt = 0; mt < 2; ++mt)
        acc2[mt][nt] = __builtin_amdgcn_mfma_f32_16x16x32_bf16(a[mt], bb, acc2[mt][nt], 0, 0, 0);
    }
    if (sp + 4 < 20) {
      asm volatile("s_waitcnt lgkmcnt(0)" ::: "memory");
      __builtin_amdgcn_sched_barrier(0);
      stage_w(W2, wbuf[sp & 3], wv, lane, sp + 4);
    }
  }

  // ---- combine + store ----
  if (VAR == 0) {
    const float* par = inF + ((size_t)p * SEG + (size_t)b * NC) * (size_t)(2 * Tn);
    float* xo_ = outF + ((size_t)(p * 2 + g) * SEG + (size_t)b * NC) * Tn;
#pragma unroll
    for (int mt = 0; mt < 2; ++mt)
#pragma unroll
      for (int nt = 0; nt < 4; ++nt) {
        int t = t0 + nt * 16 + l15;
#pragma unroll
        for (int r = 0; r < 4; ++r) {
          int co = co_base + mt * 16 + r;
          float xv = par[(size_t)co * (2 * Tn) + 2 * t + g];   // g0: xe, g1: xo
          xo_[(size_t)co * Tn + t] = xv * __expf(ftanh(acc2[mt][nt][r]));
        }
      }
  } else {
    const float* xf = inF + ((size_t)(p * 2 + g) * SEG + (size_t)b * NC) * Tn;  // g0: xet, g1: xot
    float* ch = outF + ((size_t)(2 * p + g) * SEG + (size_t)b * NC) * Tn;
#pragma unroll
    for (int mt = 0; mt < 2; ++mt)
#pragma unroll
      for (int nt = 0; nt < 4; ++nt) {
        int t = t0 + nt * 16 + l15;
#pragma unroll
        for (int r = 0; r < 4; ++r) {
          int co = co_base + mt * 16 + r;
          float cv = ftanh(acc2[mt][nt][r]);
          float base = xf[(size_t)co * Tn + t];
          ch[(size_t)co * Tn + t] = g ? (base - cv) : (base + cv);
        }
      }
  }
}

// ---------------- final projection + denorm (gathers leaf layout) ----------------
__global__ void final_kernel(const float* __restrict__ dect, const float* __restrict__ xt,
                             const float* __restrict__ projw, const float* __restrict__ means,
                             const float* __restrict__ stdev, float* __restrict__ out) {
  int b = blockIdx.x, p = blockIdx.y;
  int tid = threadIdx.x;
  const float* w = projw + (size_t)(1024 + p) * 1024;
  const float* x0 = xt + (size_t)b * NC * NL;
  float a[3] = {0.f, 0.f, 0.f};
  for (int l = tid; l < 1024; l += 256) {
    float wv = w[l];
    int rl = l & 7;
    int pb = ((rl & 1) << 2) | (rl & 2) | (rl >> 2);
    int br = (l >> 3) & 1;
    int t = l >> 4;
    const float* dl = dect + ((size_t)(2 * pb + br) * NB + b) * NC * 64 + t;
#pragma unroll
    for (int cc = 0; cc < 3; ++cc)
      a[cc] += wv * (dl[(size_t)cc * 64] + x0[(size_t)cc * NL + l]);
  }
  __shared__ float red[3][256];
  for (int cc = 0; cc < 3; ++cc) red[cc][tid] = a[cc];
  __syncthreads();
  for (int off = 128; off > 0; off >>= 1) {
    if (tid < off) {
      red[0][tid] += red[0][tid + off];
      red[1][tid] += red[1][tid + off];
      red[2][tid] += red[2][tid + off];
    }
    __syncthreads();
  }
  if (tid < 3) {
    out[((size_t)b * NP + p) * 3 + tid] = red[tid][0] * stdev[b * NC + tid] + means[b * NC + tid];
  }
}

}  // namespace

extern "C" void kernel_launch(void* const* d_in, const int* in_sizes, int n_in,
                              void* d_out, int out_size, void* d_ws, size_t ws_size,
                              hipStream_t stream) {
  (void)in_sizes; (void)n_in; (void)out_size; (void)ws_size;
  const float* x_enc = (const float*)d_in[0];
  const float* mask  = (const float*)d_in[1];
  const float* fc1_w = (const float*)d_in[2];
  const float* fc2_w = (const float*)d_in[3];
  const float* ln_g  = (const float*)d_in[4];
  const float* ln_b  = (const float*)d_in[5];
  const float* w1    = (const float*)d_in[6];
  const float* b1    = (const float*)d_in[7];
  const float* w2    = (const float*)d_in[8];
  const float* b2    = (const float*)d_in[9];
  const float* projw = (const float*)d_in[10];
  float* out = (float*)d_out;
  float* ws = (float*)d_ws;

  // workspace layout (floats); total ~104 MB
  float* means = ws + 0;          // 4096
  float* stdev = ws + 4096;       // 4096
  float* x_t   = ws + 8192;       // 4,194,304  (B,C,L) fp32, depth-0 parent + residual
  float* freq  = ws + 4202496;    // 4,194,304  lr fp32; depth-3 parent
  float* IN1   = ws + 8396800;    // 4,194,304  hid_bf; depth-1 parent; dect
  float* IN2   = ws + 12591104;   // 4,194,304  fc weights bf16; depth-2 parent
  float* xeof  = ws + 16785408;   // 4,194,304  freq_bf early; xeo fp32 [p*2+g][B][C][Tn]
  float* wp1f  = ws + 20979712;   // 2,457,600  packed conv w1 bf16
  float* wp2f  = ws + 23437312;   // 2,457,600  packed conv w2 bf16; stats partials early
  float* dect = IN1;
  float* stats_part = wp2f;
  u16* freq_bf = (u16*)xeof;
  u16* hid_bf  = (u16*)IN1;
  u16* fc1w_bf = (u16*)IN2;
  u16* fc2w_bf = (u16*)(IN2 + 1048576);
  u16* wp1 = (u16*)wp1f;
  u16* wp2 = (u16*)wp2f;

  stats1<<<dim3(NB, 16), 256, 0, stream>>>(x_enc, mask, stats_part);
  norm_transpose<<<dim3(NB, NL / 32, NC / 32), dim3(32, 8), 0, stream>>>(
      x_enc, mask, stats_part, means, stdev, x_t);
  prep3<<<15872, 256, 0, stream>>>(x_t, freq_bf, fc1_w, fc2_w, fc1w_bf, fc2w_bf,
                                   w1, w2, wp1, wp2);

  // gemm1: 128x128 tiles, grid 16n x 32m; XCD chunk 8m x 8n (cnch=2).
  gemm_n128<<<dim3(16, 32), 256, 0, stream>>>(freq_bf, fc1w_bf, hid_bf,
                                              4096, 2048, 1024, 8, 8);
  // gemm2: 128x64 tiles, grid 16n x 32m; XCD chunk 8m x 8n.
  gemm_mfma<<<dim3(16, 32), 256, 0, stream>>>(hid_bf, fc2w_bf, freq,
                                              4096, 1024, 2048, 8, 8);

  ln_combine<<<4096, 256, 0, stream>>>(freq, x_t, ln_g, ln_b);

  // tree: depth buffers x_t -> IN1 -> IN2 -> freq -> IN1(dect); 2 fused launches per depth
  float* dbuf[5] = {x_t, IN1, IN2, freq, IN1};
  for (int d = 0; d < 4; ++d) {
    int Tn = 512 >> d;
    int nsub = 1 << d;
    dim3 grd(NB, Tn / CT, 2 * nsub);   // 512 blocks at every depth
    ccb_fused<0><<<grd, 256, 0, stream>>>(dbuf[d], xeof, wp1, wp2, b1, b2, d, Tn);
    ccb_fused<1><<<grd, 256, 0, stream>>>(xeof, dbuf[d + 1], wp1, wp2, b1, b2, d, Tn);
  }

  final_kernel<<<dim3(NB, NP), 256, 0, stream>>>(dect, x_t, projw, means, stdev, out);
}